// Round 6
// baseline (940.217 us; speedup 1.0000x reference)
//
#include <hip/hip_runtime.h>
#include <hip/hip_bf16.h>
#include <math.h>

#define NN 2048
#define NEG_SLOPE 0.2f
#define NBLK 512u

typedef __attribute__((ext_vector_type(8))) short bf16x8;
typedef __attribute__((ext_vector_type(4))) float f32x4;

static __device__ inline short f2bf(float x) {
  union { float f; unsigned u; } v;
  v.f = x;
  unsigned r = v.u + 0x7fffu + ((v.u >> 16) & 1u);  // RNE
  return (short)(r >> 16);
}

// All device pointers for the mega kernel.
struct MP {
  const float* x; const float* attn; const int* bidx;
  const float* conv_w; const float* conv_b;
  const float* W1; const float* asrc1; const float* adst1;
  const float* ae1; const float* We1; const float* b1;
  const float* W2; const float* asrc2; const float* adst2;
  const float* ae2; const float* We2; const float* b2;
  const float* fcw; const float* fcb;
  float* aggT; float* num1; float* num2; float* feat2;
  float* colsum; float* colcnt;
  float* ssrc1; float* sdst1; float* ssrc2; float* sdst2;
  unsigned* bar; float* ce; float* d1; float* d2;
  __hip_bfloat16* xb; __hip_bfloat16* w1t; __hip_bfloat16* w2t;
  __hip_bfloat16* hTsw1; __hip_bfloat16* hTsw2; __hip_bfloat16* feat1b;
  float* out;
};

// Zero atomic accumulators + barrier counter (24576 stats + 16 bar slots).
__global__ __launch_bounds__(256) void k_init(float* p) {
  int i = blockIdx.x * 256 + threadIdx.x;
  if (i < 24592) p[i] = 0.f;
}

// Device-scope grid barrier: all NBLK blocks co-resident (persistent kernel).
__device__ __forceinline__ void gbar(unsigned* bar, unsigned target) {
  __syncthreads();
  __threadfence();
  if (threadIdx.x == 0) {
    atomicAdd(bar, 1u);
    while (atomicAdd(bar, 0u) < target) { __builtin_amdgcn_s_sleep(8); }
  }
  __syncthreads();
  __threadfence();
}

__global__ __launch_bounds__(256, 2) void mega(MP p) {
  const int tid = threadIdx.x;
  const unsigned bid = blockIdx.x;
  const unsigned gt = bid * 256u + (unsigned)tid;  // < 131072
  __shared__ float ss_sh[2048];

  // ============ P0: xb (fp32->bf16), w1t, w2t transposed bf16, ce ============
  if (gt < 65536u) {
    f32x4 v = *(const f32x4*)(p.x + (size_t)gt * 4);
    short4 o;
    o.x = f2bf(v[0]); o.y = f2bf(v[1]); o.z = f2bf(v[2]); o.w = f2bf(v[3]);
    *(short4*)((short*)p.xb + (size_t)gt * 4) = o;
  } else {
    unsigned o = gt - 65536u;  // < 65536
    ((short*)p.w1t)[o] = f2bf(p.W1[(o & 127u) * 512u + (o >> 7)]);
    ((short*)p.w2t)[o] = f2bf(p.W2[(o & 511u) * 128u + (o >> 9)]);
  }
  if (bid == 511u) {
    const int lane = tid & 63;
    const int wv = tid >> 6;
    float q1 = p.ae1[wv * 128 + lane] * p.We1[wv * 128 + lane] +
               p.ae1[wv * 128 + 64 + lane] * p.We1[wv * 128 + 64 + lane];
    for (int off = 32; off; off >>= 1) q1 += __shfl_down(q1, off);
    if (lane == 0) p.ce[wv] = q1;
    float q2 = p.ae2[lane] * p.We2[lane] + p.ae2[64 + lane] * p.We2[64 + lane];
    for (int off = 32; off; off >>= 1) q2 += __shfl_down(q2, off);
    if (tid == 0) p.ce[4] = q2;
  }
  gbar(p.bar, NBLK * 1u);

  // ============ P1: agg conv -> aggT (transposed) + column stats ============
  {
    const int bx = (int)(bid & 1u);
    const int by = (int)(bid >> 1);         // 0..255
    const int t = bx * 1024 + tid * 4;
    const int s0 = by * 8;
    float w[12];
#pragma unroll
    for (int c = 0; c < 12; ++c) w[c] = p.conv_w[c];
    const float cb = p.conv_b[0];
    f32x4 acc[8];
#pragma unroll
    for (int s = 0; s < 8; ++s) acc[s] = (f32x4){cb, cb, cb, cb};
    for (int c = 0; c < 12; ++c) {
      const float* base = p.attn + (size_t)c * NN * NN + (size_t)s0 * NN + t;
#pragma unroll
      for (int s = 0; s < 8; ++s) {
        f32x4 v = *(const f32x4*)(base + (size_t)s * NN);
        acc[s] += w[c] * v;
      }
    }
#pragma unroll
    for (int j = 0; j < 4; ++j) {
      f32x4 lo = {acc[0][j], acc[1][j], acc[2][j], acc[3][j]};
      f32x4 hi = {acc[4][j], acc[5][j], acc[6][j], acc[7][j]};
      float* orow = p.aggT + (size_t)(t + j) * NN + s0;
      *(f32x4*)orow = lo;
      *(f32x4*)(orow + 4) = hi;
    }
#pragma unroll
    for (int j = 0; j < 4; ++j) {
      float psum = 0.f, pcnt = 0.f;
#pragma unroll
      for (int s = 0; s < 8; ++s) {
        float a = acc[s][j];
        bool m = (a > 0.f) && (s0 + s != t + j);
        psum += m ? a : 0.f;
        pcnt += m ? 1.f : 0.f;
      }
      atomicAdd(p.colsum + t + j, psum);
      atomicAdd(p.colcnt + t + j, pcnt);
    }
  }
  gbar(p.bar, NBLK * 2u);

  // ============ P2: gemm1 (xb @ w1t^T) -> hTsw1 + fused ssrc1/sdst1 ============
  {
    const int w = (int)(bid * 4u) + (tid >> 6);   // 0..2047
    const int lane = tid & 63, row = lane & 15, kg = lane >> 4;
    const int mb = w >> 4, nb = w & 15;           // 128 x 16 units
    const int m0 = mb * 16, n0 = nb * 32;
    const __hip_bfloat16* arow = p.xb + (size_t)(m0 + row) * 128 + kg * 8;
    f32x4 acc[2];
#pragma unroll
    for (int f = 0; f < 2; ++f) acc[f] = (f32x4){0.f, 0.f, 0.f, 0.f};
#pragma unroll
    for (int ks = 0; ks < 4; ++ks) {
      bf16x8 Af = *(const bf16x8*)(arow + ks * 32);
#pragma unroll
      for (int f = 0; f < 2; ++f) {
        bf16x8 Bf = *(const bf16x8*)(p.w1t + (size_t)(n0 + f * 16 + row) * 128 +
                                     kg * 8 + ks * 32);
        acc[f] = __builtin_amdgcn_mfma_f32_16x16x32_bf16(Af, Bf, acc[f], 0, 0, 0);
      }
    }
    const int h = nb >> 2;
    float as[2], ad[2];
#pragma unroll
    for (int f = 0; f < 2; ++f) {
      int ch = (n0 + f * 16 + row) & 127;
      as[f] = p.asrc1[h * 128 + ch];
      ad[f] = p.adst1[h * 128 + ch];
    }
    float ps[4] = {0.f, 0.f, 0.f, 0.f}, pd[4] = {0.f, 0.f, 0.f, 0.f};
#pragma unroll
    for (int f = 0; f < 2; ++f)
#pragma unroll
      for (int r = 0; r < 4; ++r) {
        ps[r] += acc[f][r] * as[f];
        pd[r] += acc[f][r] * ad[f];
      }
#pragma unroll
    for (int m = 1; m < 16; m <<= 1) {
#pragma unroll
      for (int r = 0; r < 4; ++r) {
        ps[r] += __shfl_xor(ps[r], m);
        pd[r] += __shfl_xor(pd[r], m);
      }
    }
    if (row == 0) {
#pragma unroll
      for (int r = 0; r < 4; ++r) {
        int node = m0 + kg * 4 + r;
        atomicAdd(&p.ssrc1[node * 4 + h], ps[r]);
        atomicAdd(&p.sdst1[node * 4 + h], pd[r]);
      }
    }
#pragma unroll
    for (int f = 0; f < 2; ++f) {
      const int cbi = nb * 2 + f;
      short4 ct;
      ct.x = f2bf(acc[f][0]); ct.y = f2bf(acc[f][1]);
      ct.z = f2bf(acc[f][2]); ct.w = f2bf(acc[f][3]);
      size_t a4 = (size_t)cbi * (NN * 16) +
                  (size_t)(((m0 >> 3) + (kg >> 1)) * 128 + row * 8 + (kg & 1) * 4);
      *(short4*)((short*)p.hTsw1 + a4) = ct;
    }
  }
  gbar(p.bar, NBLK * 3u);

  // ============ P3: attn1 (4 heads/block, 16 targets, splits=4) ============
  {
    const int t0 = (int)(bid & 127u) * 16;
    const int split = (int)(bid >> 7);        // 0..3
    const int sbeg = split * 512;
    for (int i = tid; i < 2048; i += 256) {
      int hh = i >> 9, s = i & 511;
      ss_sh[hh * 512 + s] = p.ssrc1[(sbeg + s) * 4 + hh];
    }
    __syncthreads();
    const int lane = tid & 63, h = tid >> 6, row = lane & 15, kg = lane >> 4;
    const int tRow = t0 + row;
    const float ce = p.ce[h];
    const float sd_t = p.sdst1[tRow * 4 + h];
    const float ma_t = p.colsum[tRow] / fmaxf(p.colcnt[tRow], 1.f);
    const float* arow = p.aggT + (size_t)tRow * NN;
    const float* ssh = ss_sh + h * 512;
    const __hip_bfloat16* bbase =
        p.hTsw1 + (size_t)(h * 8) * (NN * 16) + kg * 128 + row * 8;
    f32x4 acc[8];
#pragma unroll
    for (int f = 0; f < 8; ++f) acc[f] = (f32x4){0.f, 0.f, 0.f, 0.f};
    float dpart = 0.f;
    for (int s0 = sbeg; s0 < sbeg + 512; s0 += 32) {
      const int sk = s0 + kg * 8;
      f32x4 a0 = *(const f32x4*)(arow + sk);
      f32x4 a1 = *(const f32x4*)(arow + sk + 4);
      f32x4 sv0 = *(const f32x4*)(ssh + (sk - sbeg));
      f32x4 sv1 = *(const f32x4*)(ssh + (sk - sbeg) + 4);
      float av[8] = {a0[0], a0[1], a0[2], a0[3], a1[0], a1[1], a1[2], a1[3]};
      float sv[8] = {sv0[0], sv0[1], sv0[2], sv0[3], sv1[0], sv1[1], sv1[2], sv1[3]};
      short pb[8];
#pragma unroll
      for (int j = 0; j < 8; ++j) {
        const int s = sk + j;
        const float a = av[j];
        const bool diag = (s == tRow);
        const float ev = diag ? ma_t : a;
        const bool adj = diag || (a > 0.f);
        float l = sv[j] + sd_t + ev * ce;
        l = fmaxf(l, NEG_SLOPE * l);
        const float pv = adj ? __expf(l) : 0.f;
        dpart += pv;
        pb[j] = f2bf(pv);
      }
      bf16x8 A = {pb[0], pb[1], pb[2], pb[3], pb[4], pb[5], pb[6], pb[7]};
      const __hip_bfloat16* bp = bbase + (size_t)s0 * 16;
#pragma unroll
      for (int f = 0; f < 8; ++f) {
        bf16x8 B = *(const bf16x8*)(bp + (size_t)f * (NN * 16));
        acc[f] = __builtin_amdgcn_mfma_f32_16x16x32_bf16(A, B, acc[f], 0, 0, 0);
      }
    }
    dpart += __shfl_xor(dpart, 16);
    dpart += __shfl_xor(dpart, 32);
    if (lane < 16) p.d1[((size_t)split * NN + tRow) * 4 + h] = dpart;
#pragma unroll
    for (int f = 0; f < 8; ++f) {
      const int col = h * 128 + f * 16 + row;
#pragma unroll
      for (int r = 0; r < 4; ++r) {
        const int trow = t0 + kg * 4 + r;
        p.num1[((size_t)split * NN + trow) * 512 + col] = acc[f][r];
      }
    }
  }
  gbar(p.bar, NBLK * 4u);

  // ============ P4: combine1 -> ReLU -> bf16 feat1b ============
  {
    const size_t TOT = (size_t)NN * 512;
    for (size_t e = gt; e < TOT; e += 131072u) {
      int t = (int)(e >> 9), j = (int)(e & 511);
      int h = j >> 7;
      float nsum = 0.f, dsum = 0.f;
#pragma unroll
      for (int q = 0; q < 4; ++q) nsum += p.num1[(size_t)q * TOT + e];
#pragma unroll
      for (int q = 0; q < 4; ++q) dsum += p.d1[((size_t)q * NN + t) * 4 + h];
      float v = nsum / dsum + p.b1[j];
      p.feat1b[e] = __float2bfloat16(v > 0.f ? v : 0.f);
    }
  }
  gbar(p.bar, NBLK * 5u);

  // ============ P5: gemm2 (feat1b @ w2t^T) -> hTsw2 + ssrc2/sdst2 ============
  {
    const int w = (int)(bid * 4u) + (tid >> 6);
    if (w < 512) {
      const int lane = tid & 63, row = lane & 15, kg = lane >> 4;
      const int mb = w >> 2, nb = w & 3;          // 128 x 4 units
      const int m0 = mb * 16, n0 = nb * 32;
      const __hip_bfloat16* arow = p.feat1b + (size_t)(m0 + row) * 512 + kg * 8;
      f32x4 acc[2];
#pragma unroll
      for (int f = 0; f < 2; ++f) acc[f] = (f32x4){0.f, 0.f, 0.f, 0.f};
#pragma unroll
      for (int ks = 0; ks < 16; ++ks) {
        bf16x8 Af = *(const bf16x8*)(arow + ks * 32);
#pragma unroll
        for (int f = 0; f < 2; ++f) {
          bf16x8 Bf = *(const bf16x8*)(p.w2t + (size_t)(n0 + f * 16 + row) * 512 +
                                       kg * 8 + ks * 32);
          acc[f] = __builtin_amdgcn_mfma_f32_16x16x32_bf16(Af, Bf, acc[f], 0, 0, 0);
        }
      }
      float as[2], ad[2];
#pragma unroll
      for (int f = 0; f < 2; ++f) {
        int ch = (n0 + f * 16 + row) & 127;
        as[f] = p.asrc2[ch];
        ad[f] = p.adst2[ch];
      }
      float ps[4] = {0.f, 0.f, 0.f, 0.f}, pd[4] = {0.f, 0.f, 0.f, 0.f};
#pragma unroll
      for (int f = 0; f < 2; ++f)
#pragma unroll
        for (int r = 0; r < 4; ++r) {
          ps[r] += acc[f][r] * as[f];
          pd[r] += acc[f][r] * ad[f];
        }
#pragma unroll
      for (int m = 1; m < 16; m <<= 1) {
#pragma unroll
        for (int r = 0; r < 4; ++r) {
          ps[r] += __shfl_xor(ps[r], m);
          pd[r] += __shfl_xor(pd[r], m);
        }
      }
      if (row == 0) {
#pragma unroll
        for (int r = 0; r < 4; ++r) {
          int node = m0 + kg * 4 + r;
          atomicAdd(&p.ssrc2[node], ps[r]);
          atomicAdd(&p.sdst2[node], pd[r]);
        }
      }
#pragma unroll
      for (int f = 0; f < 2; ++f) {
        const int cbi = nb * 2 + f;
        short4 ct;
        ct.x = f2bf(acc[f][0]); ct.y = f2bf(acc[f][1]);
        ct.z = f2bf(acc[f][2]); ct.w = f2bf(acc[f][3]);
        size_t a4 = (size_t)cbi * (NN * 16) +
                    (size_t)(((m0 >> 3) + (kg >> 1)) * 128 + row * 8 + (kg & 1) * 4);
        *(short4*)((short*)p.hTsw2 + a4) = ct;
      }
    }
  }
  gbar(p.bar, NBLK * 6u);

  // ============ P6: attn2 (1 head, 32 targets/block, splits=8) ============
  {
    const int t0 = (int)(bid & 63u) * 32;
    const int split = (int)(bid >> 6);        // 0..7
    const int sbeg = split * 256;
    for (int i = tid; i < 256; i += 256) ss_sh[i] = p.ssrc2[sbeg + i];
    __syncthreads();
    const int lane = tid & 63, w = tid >> 6;
    const int wm = w & 1, wn = w >> 1;
    const int m0 = t0 + wm * 16;
    const int row = lane & 15, kg = lane >> 4;
    const int tRow = m0 + row;
    const float ce = p.ce[4];
    const float sd_t = p.sdst2[tRow];
    const float ma_t = p.colsum[tRow] / fmaxf(p.colcnt[tRow], 1.f);
    const float* arow = p.aggT + (size_t)tRow * NN;
    const __hip_bfloat16* bbase =
        p.hTsw2 + (size_t)(wn * 4) * (NN * 16) + kg * 128 + row * 8;
    f32x4 acc[4];
#pragma unroll
    for (int f = 0; f < 4; ++f) acc[f] = (f32x4){0.f, 0.f, 0.f, 0.f};
    float dpart = 0.f;
    for (int s0 = sbeg; s0 < sbeg + 256; s0 += 32) {
      const int sk = s0 + kg * 8;
      f32x4 a0 = *(const f32x4*)(arow + sk);
      f32x4 a1 = *(const f32x4*)(arow + sk + 4);
      f32x4 sv0 = *(const f32x4*)(ss_sh + (sk - sbeg));
      f32x4 sv1 = *(const f32x4*)(ss_sh + (sk - sbeg) + 4);
      float av[8] = {a0[0], a0[1], a0[2], a0[3], a1[0], a1[1], a1[2], a1[3]};
      float sv[8] = {sv0[0], sv0[1], sv0[2], sv0[3], sv1[0], sv1[1], sv1[2], sv1[3]};
      short pb[8];
#pragma unroll
      for (int j = 0; j < 8; ++j) {
        const int s = sk + j;
        const float a = av[j];
        const bool diag = (s == tRow);
        const float ev = diag ? ma_t : a;
        const bool adj = diag || (a > 0.f);
        float l = sv[j] + sd_t + ev * ce;
        l = fmaxf(l, NEG_SLOPE * l);
        const float pv = adj ? __expf(l) : 0.f;
        dpart += pv;
        pb[j] = f2bf(pv);
      }
      bf16x8 A = {pb[0], pb[1], pb[2], pb[3], pb[4], pb[5], pb[6], pb[7]};
      const __hip_bfloat16* bp = bbase + (size_t)s0 * 16;
#pragma unroll
      for (int f = 0; f < 4; ++f) {
        bf16x8 B = *(const bf16x8*)(bp + (size_t)f * (NN * 16));
        acc[f] = __builtin_amdgcn_mfma_f32_16x16x32_bf16(A, B, acc[f], 0, 0, 0);
      }
    }
    dpart += __shfl_xor(dpart, 16);
    dpart += __shfl_xor(dpart, 32);
    if (wn == 0 && lane < 16) p.d2[(size_t)split * NN + tRow] = dpart;
#pragma unroll
    for (int f = 0; f < 4; ++f) {
      const int col = wn * 64 + f * 16 + row;
#pragma unroll
      for (int r = 0; r < 4; ++r) {
        const int trow = m0 + kg * 4 + r;
        p.num2[((size_t)split * NN + trow) * 128 + col] = acc[f][r];
      }
    }
  }
  gbar(p.bar, NBLK * 7u);

  // ============ P7: combine2 -> fp32 feat2 ============
  {
    const size_t TOT = (size_t)NN * 128;
    for (size_t e = gt; e < TOT; e += 131072u) {
      int t = (int)(e >> 7), c = (int)(e & 127);
      float nsum = 0.f, dsum = 0.f;
#pragma unroll
      for (int q = 0; q < 8; ++q) nsum += p.num2[(size_t)q * TOT + e];
#pragma unroll
      for (int q = 0; q < 8; ++q) dsum += p.d2[(size_t)q * NN + t];
      p.feat2[e] = nsum / dsum + p.b2[c];
    }
  }
  gbar(p.bar, NBLK * 8u);

  // ============ P8: pool + fc + log_softmax (blocks 0..7) ============
  if (bid < 8u) {
    const int g = (int)bid;
    __shared__ int lo[2];
    __shared__ float ps2[256];
    __shared__ float lsh[10];
    if (tid == 0) { lo[0] = NN; lo[1] = NN; }
    __syncthreads();
    for (int n = tid; n < NN; n += 256) {
      int b = p.bidx[n];
      int bprev = (n == 0) ? -1 : p.bidx[n - 1];
      if (b >= g && bprev < g) atomicMin(&lo[0], n);
      if (b >= g + 1 && bprev < g + 1) atomicMin(&lo[1], n);
    }
    __syncthreads();
    int s = lo[0], e = lo[1];
    const int c = tid & 127, half = tid >> 7;
    float sum = 0.f;
    for (int n = s + half; n < e; n += 2) sum += p.feat2[(size_t)n * 128 + c];
    ps2[tid] = sum;
    __syncthreads();
    if (tid < 128) {
      float cntf = (float)((e - s) > 1 ? (e - s) : 1);
      ps2[tid] = (ps2[tid] + ps2[tid + 128]) / cntf;
    }
    __syncthreads();
    if (tid < 10) {
      float v = p.fcb[tid];
      for (int ch = 0; ch < 128; ++ch) v += ps2[ch] * p.fcw[ch * 10 + tid];
      lsh[tid] = v;
    }
    __syncthreads();
    if (tid < 10) {
      float m = -1e30f;
      for (int i = 0; i < 10; ++i) m = fmaxf(m, lsh[i]);
      float den = 0.f;
      for (int i = 0; i < 10; ++i) den += expf(lsh[i] - m);
      p.out[g * 10 + tid] = lsh[tid] - m - logf(den);
    }
  }
}

extern "C" void kernel_launch(void* const* d_in, const int* in_sizes, int n_in,
                              void* d_out, int out_size, void* d_ws,
                              size_t ws_size, hipStream_t stream) {
  (void)in_sizes; (void)n_in; (void)out_size; (void)ws_size;
  float* ws = (float*)d_ws;
  MP p;
  p.x      = (const float*)d_in[0];
  p.attn   = (const float*)d_in[1];
  p.bidx   = (const int*)d_in[2];
  p.conv_w = (const float*)d_in[3];
  p.conv_b = (const float*)d_in[4];
  p.W1     = (const float*)d_in[5];
  p.asrc1  = (const float*)d_in[6];
  p.adst1  = (const float*)d_in[7];
  p.ae1    = (const float*)d_in[8];
  p.We1    = (const float*)d_in[9];
  p.b1     = (const float*)d_in[10];
  p.W2     = (const float*)d_in[11];
  p.asrc2  = (const float*)d_in[12];
  p.adst2  = (const float*)d_in[13];
  p.ae2    = (const float*)d_in[14];
  p.We2    = (const float*)d_in[15];
  p.b2     = (const float*)d_in[16];
  p.fcw    = (const float*)d_in[17];
  p.fcb    = (const float*)d_in[18];

  p.aggT   = ws;                       // 4,194,304
  p.num1   = p.aggT + 4194304;         // 4,194,304 (4 x 2048 x 512)
  p.num2   = p.num1 + 4194304;         // 2,097,152 (8 x 2048 x 128)
  p.feat2  = p.num2 + 2097152;         //   262,144
  p.colsum = p.feat2 + 262144;         //     2,048  <- zero region start
  p.colcnt = p.colsum + 2048;          //     2,048
  p.ssrc1  = p.colcnt + 2048;          //     8,192
  p.sdst1  = p.ssrc1 + 8192;           //     8,192
  p.ssrc2  = p.sdst1 + 8192;           //     2,048
  p.sdst2  = p.ssrc2 + 2048;           //     2,048
  p.bar    = (unsigned*)(p.sdst2 + 2048);  // 16 slots (zeroed with stats)
  p.ce     = (float*)p.bar + 16;       //        64
  p.d1     = p.ce + 64;                //    32,768 (4 x 2048 x 4)
  p.d2     = p.d1 + 32768;             //    16,384 (8 x 2048)
  float* bf = p.d2 + 16384;
  p.xb     = (__hip_bfloat16*)bf;               // 262,144 el
  p.w1t    = (__hip_bfloat16*)(bf + 131072);    //  65,536 el
  p.w2t    = (__hip_bfloat16*)(bf + 163840);    //  65,536 el
  p.hTsw1  = (__hip_bfloat16*)(bf + 196608);    // 1,048,576 el
  p.hTsw2  = (__hip_bfloat16*)(bf + 720896);    //   262,144 el
  p.feat1b = (__hip_bfloat16*)(bf + 851968);    // 1,048,576 el
  p.out    = (float*)d_out;

  k_init<<<97, 256, 0, stream>>>(p.colsum);
  mega<<<NBLK, 256, 0, stream>>>(p);
}

// Round 7
// 524.001 us; speedup vs baseline: 1.7943x; 1.7943x over previous
//
#include <hip/hip_runtime.h>
#include <hip/hip_bf16.h>
#include <math.h>

#define NN 2048
#define NEG_SLOPE 0.2f
#define NBLK 512u

typedef __attribute__((ext_vector_type(8))) short bf16x8;
typedef __attribute__((ext_vector_type(4))) float f32x4;

static __device__ inline short f2bf(float x) {
  union { float f; unsigned u; } v;
  v.f = x;
  unsigned r = v.u + 0x7fffu + ((v.u >> 16) & 1u);  // RNE
  return (short)(r >> 16);
}

// All device pointers for the mega kernel.
struct MP {
  const float* x; const float* attn; const int* bidx;
  const float* conv_w; const float* conv_b;
  const float* W1; const float* asrc1; const float* adst1;
  const float* ae1; const float* We1; const float* b1;
  const float* W2; const float* asrc2; const float* adst2;
  const float* ae2; const float* We2; const float* b2;
  const float* fcw; const float* fcb;
  float* aggT; float* feat2;
  float* colsum; float* colcnt;
  float* ssrc1; float* sdst1; float* ssrc2; float* sdst2;
  unsigned* bar; float* ce;
  __hip_bfloat16* xb; __hip_bfloat16* w1t; __hip_bfloat16* w2t;
  __hip_bfloat16* hTsw1; __hip_bfloat16* hTsw2; __hip_bfloat16* feat1b;
  float* out;
};

// Zero atomic accumulators (24576) + barrier lines (160 u32).
__global__ __launch_bounds__(256) void k_init(float* p) {
  int i = blockIdx.x * 256 + threadIdx.x;
  if (i < 24736) p[i] = 0.f;
}

// Grid barrier: tree arrival (8 padded sub-counters, read-mostly master) +
// read-only polling (no RMW spin). phase is 1-based.
__device__ __forceinline__ void gbar(unsigned* bar, unsigned phase,
                                     unsigned bid) {
  __syncthreads();
  __threadfence();
  if (threadIdx.x == 0) {
    unsigned* sub = bar + (1u + (bid & 7u)) * 16u;
    unsigned old = __hip_atomic_fetch_add(sub, 1u, __ATOMIC_RELAXED,
                                          __HIP_MEMORY_SCOPE_AGENT);
    if (old == phase * 64u - 1u)
      __hip_atomic_fetch_add(bar, 1u, __ATOMIC_RELAXED,
                             __HIP_MEMORY_SCOPE_AGENT);
    while (__hip_atomic_load(bar, __ATOMIC_RELAXED,
                             __HIP_MEMORY_SCOPE_AGENT) < phase * 8u)
      __builtin_amdgcn_s_sleep(16);
  }
  __syncthreads();
  __threadfence();
}

__global__ __launch_bounds__(256, 2) void mega(MP p) {
  const int tid = threadIdx.x;
  const unsigned bid = blockIdx.x;
  const unsigned gt = bid * 256u + (unsigned)tid;  // < 131072
  __shared__ float ss_sh[2048];
  __shared__ float red[4][16][128];
  __shared__ float den_sh[4][16];

  // ============ Phase A: xb/w1t/w2t/ce prep + agg conv + stats ============
  if (gt < 65536u) {
    f32x4 v = *(const f32x4*)(p.x + (size_t)gt * 4);
    short4 o;
    o.x = f2bf(v[0]); o.y = f2bf(v[1]); o.z = f2bf(v[2]); o.w = f2bf(v[3]);
    *(short4*)((short*)p.xb + (size_t)gt * 4) = o;
  } else {
    unsigned o = gt - 65536u;  // < 65536
    ((short*)p.w1t)[o] = f2bf(p.W1[(o & 127u) * 512u + (o >> 7)]);
    ((short*)p.w2t)[o] = f2bf(p.W2[(o & 511u) * 128u + (o >> 9)]);
  }
  if (bid == 511u) {
    const int lane = tid & 63;
    const int wv = tid >> 6;
    float q1 = p.ae1[wv * 128 + lane] * p.We1[wv * 128 + lane] +
               p.ae1[wv * 128 + 64 + lane] * p.We1[wv * 128 + 64 + lane];
    for (int off = 32; off; off >>= 1) q1 += __shfl_down(q1, off);
    if (lane == 0) p.ce[wv] = q1;
    float q2 = p.ae2[lane] * p.We2[lane] + p.ae2[64 + lane] * p.We2[64 + lane];
    for (int off = 32; off; off >>= 1) q2 += __shfl_down(q2, off);
    if (tid == 0) p.ce[4] = q2;
  }
  {
    const int bx = (int)(bid & 1u);
    const int by = (int)(bid >> 1);  // 0..255
    const int t = bx * 1024 + tid * 4;
    const int s0 = by * 8;
    float w[12];
#pragma unroll
    for (int c = 0; c < 12; ++c) w[c] = p.conv_w[c];
    const float cb = p.conv_b[0];
    f32x4 acc[8];
#pragma unroll
    for (int s = 0; s < 8; ++s) acc[s] = (f32x4){cb, cb, cb, cb};
    for (int c = 0; c < 12; ++c) {
      const float* base = p.attn + (size_t)c * NN * NN + (size_t)s0 * NN + t;
#pragma unroll
      for (int s = 0; s < 8; ++s) {
        f32x4 v = *(const f32x4*)(base + (size_t)s * NN);
        acc[s] += w[c] * v;
      }
    }
#pragma unroll
    for (int j = 0; j < 4; ++j) {
      f32x4 lo = {acc[0][j], acc[1][j], acc[2][j], acc[3][j]};
      f32x4 hi = {acc[4][j], acc[5][j], acc[6][j], acc[7][j]};
      float* orow = p.aggT + (size_t)(t + j) * NN + s0;
      *(f32x4*)orow = lo;
      *(f32x4*)(orow + 4) = hi;
    }
#pragma unroll
    for (int j = 0; j < 4; ++j) {
      float psum = 0.f, pcnt = 0.f;
#pragma unroll
      for (int s = 0; s < 8; ++s) {
        float a = acc[s][j];
        bool m = (a > 0.f) && (s0 + s != t + j);
        psum += m ? a : 0.f;
        pcnt += m ? 1.f : 0.f;
      }
      atomicAdd(p.colsum + t + j, psum);
      atomicAdd(p.colcnt + t + j, pcnt);
    }
  }
  gbar(p.bar, 1u, bid);

  // ============ Phase B: gemm1 (xb @ w1t^T) -> hTsw1 + ssrc1/sdst1 ============
  {
    const int w = (int)(bid * 4u) + (tid >> 6);  // 0..2047
    const int lane = tid & 63, row = lane & 15, kg = lane >> 4;
    const int mb = w >> 4, nb = w & 15;
    const int m0 = mb * 16, n0 = nb * 32;
    const __hip_bfloat16* arow = p.xb + (size_t)(m0 + row) * 128 + kg * 8;
    f32x4 acc[2];
#pragma unroll
    for (int f = 0; f < 2; ++f) acc[f] = (f32x4){0.f, 0.f, 0.f, 0.f};
#pragma unroll
    for (int ks = 0; ks < 4; ++ks) {
      bf16x8 Af = *(const bf16x8*)(arow + ks * 32);
#pragma unroll
      for (int f = 0; f < 2; ++f) {
        bf16x8 Bf = *(const bf16x8*)(p.w1t + (size_t)(n0 + f * 16 + row) * 128 +
                                     kg * 8 + ks * 32);
        acc[f] = __builtin_amdgcn_mfma_f32_16x16x32_bf16(Af, Bf, acc[f], 0, 0, 0);
      }
    }
    const int h = nb >> 2;
    float as[2], ad[2];
#pragma unroll
    for (int f = 0; f < 2; ++f) {
      int ch = (n0 + f * 16 + row) & 127;
      as[f] = p.asrc1[h * 128 + ch];
      ad[f] = p.adst1[h * 128 + ch];
    }
    float ps[4] = {0.f, 0.f, 0.f, 0.f}, pd[4] = {0.f, 0.f, 0.f, 0.f};
#pragma unroll
    for (int f = 0; f < 2; ++f)
#pragma unroll
      for (int r = 0; r < 4; ++r) {
        ps[r] += acc[f][r] * as[f];
        pd[r] += acc[f][r] * ad[f];
      }
#pragma unroll
    for (int m = 1; m < 16; m <<= 1) {
#pragma unroll
      for (int r = 0; r < 4; ++r) {
        ps[r] += __shfl_xor(ps[r], m);
        pd[r] += __shfl_xor(pd[r], m);
      }
    }
    if (row == 0) {
#pragma unroll
      for (int r = 0; r < 4; ++r) {
        int node = m0 + kg * 4 + r;
        atomicAdd(&p.ssrc1[node * 4 + h], ps[r]);
        atomicAdd(&p.sdst1[node * 4 + h], pd[r]);
      }
    }
#pragma unroll
    for (int f = 0; f < 2; ++f) {
      const int cbi = nb * 2 + f;
      short4 ct;
      ct.x = f2bf(acc[f][0]); ct.y = f2bf(acc[f][1]);
      ct.z = f2bf(acc[f][2]); ct.w = f2bf(acc[f][3]);
      size_t a4 = (size_t)cbi * (NN * 16) +
                  (size_t)(((m0 >> 3) + (kg >> 1)) * 128 + row * 8 + (kg & 1) * 4);
      *(short4*)((short*)p.hTsw1 + a4) = ct;
    }
  }
  gbar(p.bar, 2u, bid);

  // ==== Phase C: attn1. 512 blocks = 128 t-tiles x 4 heads; 4 waves =
  // 4 s-quarters; LDS reduce; write feat1b (bias+ReLU+bf16) directly. ====
  {
    const int t0 = (int)(bid >> 2) * 16;
    const int h = (int)(bid & 3u);
    for (int i = tid; i < 2048; i += 256) ss_sh[i] = p.ssrc1[i * 4 + h];
    __syncthreads();
    const int lane = tid & 63, w = tid >> 6, row = lane & 15, kg = lane >> 4;
    const int sbeg = w * 512;
    const int tRow = t0 + row;
    const float ce = p.ce[h];
    const float sd_t = p.sdst1[tRow * 4 + h];
    const float ma_t = p.colsum[tRow] / fmaxf(p.colcnt[tRow], 1.f);
    const float* arow = p.aggT + (size_t)tRow * NN;
    const float* ssh = ss_sh + sbeg;
    const __hip_bfloat16* bbase =
        p.hTsw1 + (size_t)(h * 8) * (NN * 16) + kg * 128 + row * 8;
    f32x4 acc[8];
#pragma unroll
    for (int f = 0; f < 8; ++f) acc[f] = (f32x4){0.f, 0.f, 0.f, 0.f};
    float dpart = 0.f;
    for (int s0 = sbeg; s0 < sbeg + 512; s0 += 32) {
      const int sk = s0 + kg * 8;
      f32x4 a0 = *(const f32x4*)(arow + sk);
      f32x4 a1 = *(const f32x4*)(arow + sk + 4);
      f32x4 sv0 = *(const f32x4*)(ssh + (sk - sbeg));
      f32x4 sv1 = *(const f32x4*)(ssh + (sk - sbeg) + 4);
      float av[8] = {a0[0], a0[1], a0[2], a0[3], a1[0], a1[1], a1[2], a1[3]};
      float sv[8] = {sv0[0], sv0[1], sv0[2], sv0[3],
                     sv1[0], sv1[1], sv1[2], sv1[3]};
      short pb[8];
#pragma unroll
      for (int j = 0; j < 8; ++j) {
        const int s = sk + j;
        const float a = av[j];
        const bool diag = (s == tRow);
        const float ev = diag ? ma_t : a;
        const bool adj = diag || (a > 0.f);
        float l = sv[j] + sd_t + ev * ce;
        l = fmaxf(l, NEG_SLOPE * l);
        const float pv = adj ? __expf(l) : 0.f;
        dpart += pv;
        pb[j] = f2bf(pv);
      }
      bf16x8 A = {pb[0], pb[1], pb[2], pb[3], pb[4], pb[5], pb[6], pb[7]};
      const __hip_bfloat16* bp = bbase + (size_t)s0 * 16;
#pragma unroll
      for (int f = 0; f < 8; ++f) {
        bf16x8 B = *(const bf16x8*)(bp + (size_t)f * (NN * 16));
        acc[f] = __builtin_amdgcn_mfma_f32_16x16x32_bf16(A, B, acc[f], 0, 0, 0);
      }
    }
    dpart += __shfl_xor(dpart, 16);
    dpart += __shfl_xor(dpart, 32);
    __syncthreads();  // ss_sh reads done before red reuse? (separate arrays; sync for store order)
#pragma unroll
    for (int f = 0; f < 8; ++f)
#pragma unroll
      for (int r = 0; r < 4; ++r) red[w][kg * 4 + r][f * 16 + row] = acc[f][r];
    if (lane < 16) den_sh[w][lane] = dpart;
    __syncthreads();
#pragma unroll
    for (int i = 0; i < 8; ++i) {
      int idx = i * 256 + tid;
      int t = idx >> 7, c = idx & 127;
      float nsum = red[0][t][c] + red[1][t][c] + red[2][t][c] + red[3][t][c];
      float dsum = den_sh[0][t] + den_sh[1][t] + den_sh[2][t] + den_sh[3][t];
      float v = nsum / dsum + p.b1[h * 128 + c];
      p.feat1b[(size_t)(t0 + t) * 512 + h * 128 + c] =
          __float2bfloat16(v > 0.f ? v : 0.f);
    }
  }
  gbar(p.bar, 3u, bid);

  // ============ Phase D: gemm2 (feat1b @ w2t^T) -> hTsw2 + ssrc2/sdst2 ============
  if (bid < 128u) {
    const int w = (int)(bid * 4u) + (tid >> 6);  // 0..511
    const int lane = tid & 63, row = lane & 15, kg = lane >> 4;
    const int mb = w >> 2, nb = w & 3;
    const int m0 = mb * 16, n0 = nb * 32;
    const __hip_bfloat16* arow = p.feat1b + (size_t)(m0 + row) * 512 + kg * 8;
    f32x4 acc[2];
#pragma unroll
    for (int f = 0; f < 2; ++f) acc[f] = (f32x4){0.f, 0.f, 0.f, 0.f};
#pragma unroll
    for (int ks = 0; ks < 16; ++ks) {
      bf16x8 Af = *(const bf16x8*)(arow + ks * 32);
#pragma unroll
      for (int f = 0; f < 2; ++f) {
        bf16x8 Bf = *(const bf16x8*)(p.w2t + (size_t)(n0 + f * 16 + row) * 512 +
                                     kg * 8 + ks * 32);
        acc[f] = __builtin_amdgcn_mfma_f32_16x16x32_bf16(Af, Bf, acc[f], 0, 0, 0);
      }
    }
    float as[2], ad[2];
#pragma unroll
    for (int f = 0; f < 2; ++f) {
      int ch = (n0 + f * 16 + row) & 127;
      as[f] = p.asrc2[ch];
      ad[f] = p.adst2[ch];
    }
    float ps[4] = {0.f, 0.f, 0.f, 0.f}, pd[4] = {0.f, 0.f, 0.f, 0.f};
#pragma unroll
    for (int f = 0; f < 2; ++f)
#pragma unroll
      for (int r = 0; r < 4; ++r) {
        ps[r] += acc[f][r] * as[f];
        pd[r] += acc[f][r] * ad[f];
      }
#pragma unroll
    for (int m = 1; m < 16; m <<= 1) {
#pragma unroll
      for (int r = 0; r < 4; ++r) {
        ps[r] += __shfl_xor(ps[r], m);
        pd[r] += __shfl_xor(pd[r], m);
      }
    }
    if (row == 0) {
#pragma unroll
      for (int r = 0; r < 4; ++r) {
        int node = m0 + kg * 4 + r;
        atomicAdd(&p.ssrc2[node], ps[r]);
        atomicAdd(&p.sdst2[node], pd[r]);
      }
    }
#pragma unroll
    for (int f = 0; f < 2; ++f) {
      const int cbi = nb * 2 + f;
      short4 ct;
      ct.x = f2bf(acc[f][0]); ct.y = f2bf(acc[f][1]);
      ct.z = f2bf(acc[f][2]); ct.w = f2bf(acc[f][3]);
      size_t a4 = (size_t)cbi * (NN * 16) +
                  (size_t)(((m0 >> 3) + (kg >> 1)) * 128 + row * 8 + (kg & 1) * 4);
      *(short4*)((short*)p.hTsw2 + a4) = ct;
    }
  }
  gbar(p.bar, 4u, bid);

  // ==== Phase E: attn2 (1 head). 128 blocks x 16 targets; 4 waves =
  // 4 s-quarters; LDS reduce; write feat2 (fp32, +b2) directly. ====
  if (bid < 128u) {
    const int t0 = (int)bid * 16;
    for (int i = tid; i < 2048; i += 256) ss_sh[i] = p.ssrc2[i];
    __syncthreads();
    const int lane = tid & 63, w = tid >> 6, row = lane & 15, kg = lane >> 4;
    const int sbeg = w * 512;
    const int tRow = t0 + row;
    const float ce = p.ce[4];
    const float sd_t = p.sdst2[tRow];
    const float ma_t = p.colsum[tRow] / fmaxf(p.colcnt[tRow], 1.f);
    const float* arow = p.aggT + (size_t)tRow * NN;
    const float* ssh = ss_sh + sbeg;
    const __hip_bfloat16* bbase = p.hTsw2 + kg * 128 + row * 8;
    f32x4 acc[8];
#pragma unroll
    for (int f = 0; f < 8; ++f) acc[f] = (f32x4){0.f, 0.f, 0.f, 0.f};
    float dpart = 0.f;
    for (int s0 = sbeg; s0 < sbeg + 512; s0 += 32) {
      const int sk = s0 + kg * 8;
      f32x4 a0 = *(const f32x4*)(arow + sk);
      f32x4 a1 = *(const f32x4*)(arow + sk + 4);
      f32x4 sv0 = *(const f32x4*)(ssh + (sk - sbeg));
      f32x4 sv1 = *(const f32x4*)(ssh + (sk - sbeg) + 4);
      float av[8] = {a0[0], a0[1], a0[2], a0[3], a1[0], a1[1], a1[2], a1[3]};
      float sv[8] = {sv0[0], sv0[1], sv0[2], sv0[3],
                     sv1[0], sv1[1], sv1[2], sv1[3]};
      short pb[8];
#pragma unroll
      for (int j = 0; j < 8; ++j) {
        const int s = sk + j;
        const float a = av[j];
        const bool diag = (s == tRow);
        const float ev = diag ? ma_t : a;
        const bool adj = diag || (a > 0.f);
        float l = sv[j] + sd_t + ev * ce;
        l = fmaxf(l, NEG_SLOPE * l);
        const float pv = adj ? __expf(l) : 0.f;
        dpart += pv;
        pb[j] = f2bf(pv);
      }
      bf16x8 A = {pb[0], pb[1], pb[2], pb[3], pb[4], pb[5], pb[6], pb[7]};
      const __hip_bfloat16* bp = bbase + (size_t)s0 * 16;
#pragma unroll
      for (int f = 0; f < 8; ++f) {
        bf16x8 B = *(const bf16x8*)(bp + (size_t)f * (NN * 16));
        acc[f] = __builtin_amdgcn_mfma_f32_16x16x32_bf16(A, B, acc[f], 0, 0, 0);
      }
    }
    dpart += __shfl_xor(dpart, 16);
    dpart += __shfl_xor(dpart, 32);
    __syncthreads();
#pragma unroll
    for (int f = 0; f < 8; ++f)
#pragma unroll
      for (int r = 0; r < 4; ++r) red[w][kg * 4 + r][f * 16 + row] = acc[f][r];
    if (lane < 16) den_sh[w][lane] = dpart;
    __syncthreads();
#pragma unroll
    for (int i = 0; i < 8; ++i) {
      int idx = i * 256 + tid;
      int t = idx >> 7, c = idx & 127;
      float nsum = red[0][t][c] + red[1][t][c] + red[2][t][c] + red[3][t][c];
      float dsum = den_sh[0][t] + den_sh[1][t] + den_sh[2][t] + den_sh[3][t];
      p.feat2[(size_t)(t0 + t) * 128 + c] = nsum / dsum + p.b2[c];
    }
  }
  gbar(p.bar, 5u, bid);

  // ============ Phase F: pool + fc + log_softmax (blocks 0..7) ============
  if (bid < 8u) {
    const int g = (int)bid;
    __shared__ int lo[2];
    __shared__ float ps2[256];
    __shared__ float lsh[10];
    if (tid == 0) { lo[0] = NN; lo[1] = NN; }
    __syncthreads();
    for (int n = tid; n < NN; n += 256) {
      int b = p.bidx[n];
      int bprev = (n == 0) ? -1 : p.bidx[n - 1];
      if (b >= g && bprev < g) atomicMin(&lo[0], n);
      if (b >= g + 1 && bprev < g + 1) atomicMin(&lo[1], n);
    }
    __syncthreads();
    int s = lo[0], e = lo[1];
    const int c = tid & 127, half = tid >> 7;
    float sum = 0.f;
    for (int n = s + half; n < e; n += 2) sum += p.feat2[(size_t)n * 128 + c];
    ps2[tid] = sum;
    __syncthreads();
    if (tid < 128) {
      float cntf = (float)((e - s) > 1 ? (e - s) : 1);
      ps2[tid] = (ps2[tid] + ps2[tid + 128]) / cntf;
    }
    __syncthreads();
    if (tid < 10) {
      float v = p.fcb[tid];
      for (int ch = 0; ch < 128; ++ch) v += ps2[ch] * p.fcw[ch * 10 + tid];
      lsh[tid] = v;
    }
    __syncthreads();
    if (tid < 10) {
      float m = -1e30f;
      for (int i = 0; i < 10; ++i) m = fmaxf(m, lsh[i]);
      float den = 0.f;
      for (int i = 0; i < 10; ++i) den += expf(lsh[i] - m);
      p.out[g * 10 + tid] = lsh[tid] - m - logf(den);
    }
  }
}

extern "C" void kernel_launch(void* const* d_in, const int* in_sizes, int n_in,
                              void* d_out, int out_size, void* d_ws,
                              size_t ws_size, hipStream_t stream) {
  (void)in_sizes; (void)n_in; (void)out_size; (void)ws_size;
  float* ws = (float*)d_ws;
  MP p;
  p.x      = (const float*)d_in[0];
  p.attn   = (const float*)d_in[1];
  p.bidx   = (const int*)d_in[2];
  p.conv_w = (const float*)d_in[3];
  p.conv_b = (const float*)d_in[4];
  p.W1     = (const float*)d_in[5];
  p.asrc1  = (const float*)d_in[6];
  p.adst1  = (const float*)d_in[7];
  p.ae1    = (const float*)d_in[8];
  p.We1    = (const float*)d_in[9];
  p.b1     = (const float*)d_in[10];
  p.W2     = (const float*)d_in[11];
  p.asrc2  = (const float*)d_in[12];
  p.adst2  = (const float*)d_in[13];
  p.ae2    = (const float*)d_in[14];
  p.We2    = (const float*)d_in[15];
  p.b2     = (const float*)d_in[16];
  p.fcw    = (const float*)d_in[17];
  p.fcb    = (const float*)d_in[18];

  p.aggT   = ws;                       // 4,194,304
  p.feat2  = p.aggT + 4194304;         //   262,144
  p.colsum = p.feat2 + 262144;         //     2,048  <- zero region start
  p.colcnt = p.colsum + 2048;          //     2,048
  p.ssrc1  = p.colcnt + 2048;          //     8,192
  p.sdst1  = p.ssrc1 + 8192;           //     8,192
  p.ssrc2  = p.sdst1 + 8192;           //     2,048
  p.sdst2  = p.ssrc2 + 2048;           //     2,048
  p.bar    = (unsigned*)(p.sdst2 + 2048);  // 160 u32 (9 padded lines, zeroed)
  p.ce     = (float*)p.bar + 160;      //        64
  float* bf = p.ce + 64;
  p.xb     = (__hip_bfloat16*)bf;               // 262,144 el
  p.w1t    = (__hip_bfloat16*)(bf + 131072);    //  65,536 el
  p.w2t    = (__hip_bfloat16*)(bf + 163840);    //  65,536 el
  p.hTsw1  = (__hip_bfloat16*)(bf + 196608);    // 1,048,576 el
  p.hTsw2  = (__hip_bfloat16*)(bf + 720896);    //   262,144 el
  p.feat1b = (__hip_bfloat16*)(bf + 851968);    // 1,048,576 el
  p.out    = (float*)d_out;

  k_init<<<97, 256, 0, stream>>>(p.colsum);
  mega<<<NBLK, 256, 0, stream>>>(p);
}

// Round 8
// 147.636 us; speedup vs baseline: 6.3685x; 3.5493x over previous
//
#include <hip/hip_runtime.h>
#include <hip/hip_bf16.h>
#include <math.h>

#define NN 2048
#define NEG_SLOPE 0.2f

typedef __attribute__((ext_vector_type(8))) short bf16x8;
typedef __attribute__((ext_vector_type(4))) float f32x4;

static __device__ inline short f2bf(float x) {
  union { float f; unsigned u; } v;
  v.f = x;
  unsigned r = v.u + 0x7fffu + ((v.u >> 16) & 1u);  // RNE
  return (short)(r >> 16);
}

// ---------------------------------------------------------------------------
// K1 k_pre: blocks 0-1023: conv -> aggT (64x64 tile, LDS transpose, coalesced
// both ways). 1024-1055: w1t bf16. 1056-1087: w2t bf16. 1088-1107: zero the
// atomic accumulators (ssrc1/sdst1/ssrc2/sdst2). 1108: ce.
// ---------------------------------------------------------------------------
__global__ __launch_bounds__(256) void k_pre(
    const float* __restrict__ attn, const float* __restrict__ conv_w,
    const float* __restrict__ conv_b, const float* __restrict__ W1,
    const float* __restrict__ W2, const float* __restrict__ ae1,
    const float* __restrict__ We1, const float* __restrict__ ae2,
    const float* __restrict__ We2, float* __restrict__ aggT,
    __hip_bfloat16* __restrict__ w1t, __hip_bfloat16* __restrict__ w2t,
    float* __restrict__ zreg, float* __restrict__ ce) {
  const int b = blockIdx.x;
  const int tid = threadIdx.x;
  if (b < 1024) {
    __shared__ float tile[64][68];
    const int t0 = (b & 31) * 64;
    const int s0 = (b >> 5) * 64;
    const int sl = tid >> 4;           // 0..15 (s within tile, +16k)
    const int t4 = (tid & 15) * 4;     // t quad
    float w[12];
#pragma unroll
    for (int c = 0; c < 12; ++c) w[c] = conv_w[c];
    const float cb = conv_b[0];
    f32x4 acc[4];
#pragma unroll
    for (int k = 0; k < 4; ++k) acc[k] = (f32x4){cb, cb, cb, cb};
    for (int c = 0; c < 12; ++c) {
      const float* base =
          attn + (size_t)c * NN * NN + (size_t)(s0 + sl) * NN + t0 + t4;
#pragma unroll
      for (int k = 0; k < 4; ++k)
        acc[k] += w[c] * *(const f32x4*)(base + (size_t)k * 16 * NN);
    }
#pragma unroll
    for (int k = 0; k < 4; ++k) *(f32x4*)&tile[sl + 16 * k][t4] = acc[k];
    __syncthreads();
    const int tl = tid >> 2;           // 0..63 (t row)
    const int sq = (tid & 3) * 16;     // s quad-of-16
    float* orow = aggT + (size_t)(t0 + tl) * NN + s0 + sq;
#pragma unroll
    for (int g = 0; g < 4; ++g) {
      f32x4 v = {tile[sq + 4 * g][tl], tile[sq + 4 * g + 1][tl],
                 tile[sq + 4 * g + 2][tl], tile[sq + 4 * g + 3][tl]};
      *(f32x4*)(orow + 4 * g) = v;
    }
  } else if (b < 1056) {
#pragma unroll
    for (int k = 0; k < 8; ++k) {
      int o = (b - 1024) * 2048 + k * 256 + tid;
      ((short*)w1t)[o] = f2bf(W1[(o & 127) * 512 + (o >> 7)]);
    }
  } else if (b < 1088) {
#pragma unroll
    for (int k = 0; k < 8; ++k) {
      int o = (b - 1056) * 2048 + k * 256 + tid;
      ((short*)w2t)[o] = f2bf(W2[(o & 511) * 128 + (o >> 9)]);
    }
  } else if (b < 1108) {
    int i = (b - 1088) * 1024 + tid * 4;
    *(f32x4*)(zreg + i) = (f32x4){0.f, 0.f, 0.f, 0.f};
  } else {
    const int lane = tid & 63;
    const int wv = tid >> 6;
    float q1 = ae1[wv * 128 + lane] * We1[wv * 128 + lane] +
               ae1[wv * 128 + 64 + lane] * We1[wv * 128 + 64 + lane];
    for (int off = 32; off; off >>= 1) q1 += __shfl_down(q1, off);
    if (lane == 0) ce[wv] = q1;
    float q2 = ae2[lane] * We2[lane] + ae2[64 + lane] * We2[64 + lane];
    for (int off = 32; off; off >>= 1) q2 += __shfl_down(q2, off);
    if (tid == 0) ce[4] = q2;
  }
}

// ---------------------------------------------------------------------------
// K2 gemm1: h1 = x @ W1 (A converted fp32->bf16 in-reg), output ONLY as
// swizzled bf16 hTsw1 + fused ssrc1/sdst1 atomics. 512 blocks x 4 waves,
// wave unit = 16 rows x 32 cols.
// ---------------------------------------------------------------------------
__global__ __launch_bounds__(256) void k_gemm1(
    const float* __restrict__ x, const __hip_bfloat16* __restrict__ w1t,
    const float* __restrict__ asrc1, const float* __restrict__ adst1,
    __hip_bfloat16* __restrict__ hTsw1, float* __restrict__ ssrc1,
    float* __restrict__ sdst1) {
  const int tid = threadIdx.x;
  const int w = (int)blockIdx.x * 4 + (tid >> 6);  // 0..2047
  const int lane = tid & 63, row = lane & 15, kg = lane >> 4;
  const int mb = w >> 4, nb = w & 15;
  const int m0 = mb * 16, n0 = nb * 32;
  const float* axrow = x + (size_t)(m0 + row) * 128 + kg * 8;
  f32x4 acc[2];
#pragma unroll
  for (int f = 0; f < 2; ++f) acc[f] = (f32x4){0.f, 0.f, 0.f, 0.f};
#pragma unroll
  for (int ks = 0; ks < 4; ++ks) {
    f32x4 xa = *(const f32x4*)(axrow + ks * 32);
    f32x4 xb = *(const f32x4*)(axrow + ks * 32 + 4);
    bf16x8 Af = {f2bf(xa[0]), f2bf(xa[1]), f2bf(xa[2]), f2bf(xa[3]),
                 f2bf(xb[0]), f2bf(xb[1]), f2bf(xb[2]), f2bf(xb[3])};
#pragma unroll
    for (int f = 0; f < 2; ++f) {
      bf16x8 Bf = *(const bf16x8*)(w1t + (size_t)(n0 + f * 16 + row) * 128 +
                                   kg * 8 + ks * 32);
      acc[f] = __builtin_amdgcn_mfma_f32_16x16x32_bf16(Af, Bf, acc[f], 0, 0, 0);
    }
  }
  const int h = nb >> 2;
  float as[2], ad[2];
#pragma unroll
  for (int f = 0; f < 2; ++f) {
    int ch = (n0 + f * 16 + row) & 127;
    as[f] = asrc1[h * 128 + ch];
    ad[f] = adst1[h * 128 + ch];
  }
  float ps[4] = {0.f, 0.f, 0.f, 0.f}, pd[4] = {0.f, 0.f, 0.f, 0.f};
#pragma unroll
  for (int f = 0; f < 2; ++f)
#pragma unroll
    for (int r = 0; r < 4; ++r) {
      ps[r] += acc[f][r] * as[f];
      pd[r] += acc[f][r] * ad[f];
    }
#pragma unroll
  for (int m = 1; m < 16; m <<= 1) {
#pragma unroll
    for (int r = 0; r < 4; ++r) {
      ps[r] += __shfl_xor(ps[r], m);
      pd[r] += __shfl_xor(pd[r], m);
    }
  }
  if (row == 0) {
#pragma unroll
    for (int r = 0; r < 4; ++r) {
      int node = m0 + kg * 4 + r;
      atomicAdd(&ssrc1[node * 4 + h], ps[r]);
      atomicAdd(&sdst1[node * 4 + h], pd[r]);
    }
  }
#pragma unroll
  for (int f = 0; f < 2; ++f) {
    const int cbi = nb * 2 + f;
    short4 ct;
    ct.x = f2bf(acc[f][0]); ct.y = f2bf(acc[f][1]);
    ct.z = f2bf(acc[f][2]); ct.w = f2bf(acc[f][3]);
    size_t a4 = (size_t)cbi * (NN * 16) +
                (size_t)(((m0 >> 3) + (kg >> 1)) * 128 + row * 8 + (kg & 1) * 4);
    *(short4*)((short*)hTsw1 + a4) = ct;
  }
}

// ---------------------------------------------------------------------------
// K3 attn1: 512 blocks = 128 t-tiles x 4 heads; 4 waves = 4 s-quarters.
// Pass 1: in-block column stats (mean_attr). Pass 2: P-on-the-fly MFMA.
// LDS reduce across waves; write feat1b (bias+ReLU+bf16) directly.
// ---------------------------------------------------------------------------
__global__ __launch_bounds__(256) void k_attn1(
    const float* __restrict__ aggT, const __hip_bfloat16* __restrict__ hTsw1,
    const float* __restrict__ ssrc1, const float* __restrict__ sdst1,
    const float* __restrict__ ce_all, const float* __restrict__ b1,
    __hip_bfloat16* __restrict__ feat1b) {
  const int tid = threadIdx.x;
  const int t0 = (int)(blockIdx.x >> 2) * 16;
  const int h = (int)(blockIdx.x & 3u);
  __shared__ float ss_sh[2048];
  __shared__ float red[4][16][128];
  __shared__ float den_sh[4][16];
  __shared__ float st_sum[4][16];
  __shared__ float st_cnt[4][16];
  for (int i = tid; i < 2048; i += 256) ss_sh[i] = ssrc1[i * 4 + h];
  __syncthreads();
  const int lane = tid & 63, w = tid >> 6, row = lane & 15, kg = lane >> 4;
  const int sbeg = w * 512;
  const int tRow = t0 + row;
  const float* arow = aggT + (size_t)tRow * NN;
  // pass 1: column stats over this wave's s-range
  {
    float psum = 0.f, pcnt = 0.f;
    for (int s0 = sbeg; s0 < sbeg + 512; s0 += 32) {
      const int sk = s0 + kg * 8;
      f32x4 a0 = *(const f32x4*)(arow + sk);
      f32x4 a1 = *(const f32x4*)(arow + sk + 4);
      float av[8] = {a0[0], a0[1], a0[2], a0[3], a1[0], a1[1], a1[2], a1[3]};
#pragma unroll
      for (int j = 0; j < 8; ++j) {
        bool m = (av[j] > 0.f) && (sk + j != tRow);
        psum += m ? av[j] : 0.f;
        pcnt += m ? 1.f : 0.f;
      }
    }
    psum += __shfl_xor(psum, 16); psum += __shfl_xor(psum, 32);
    pcnt += __shfl_xor(pcnt, 16); pcnt += __shfl_xor(pcnt, 32);
    if (lane < 16) { st_sum[w][lane] = psum; st_cnt[w][lane] = pcnt; }
  }
  __syncthreads();
  const float ma_t =
      (st_sum[0][row] + st_sum[1][row] + st_sum[2][row] + st_sum[3][row]) /
      fmaxf(st_cnt[0][row] + st_cnt[1][row] + st_cnt[2][row] + st_cnt[3][row],
            1.f);
  const float ce = ce_all[h];
  const float sd_t = sdst1[tRow * 4 + h];
  const float* ssh = ss_sh + sbeg;
  const __hip_bfloat16* bbase =
      hTsw1 + (size_t)(h * 8) * (NN * 16) + kg * 128 + row * 8;
  f32x4 acc[8];
#pragma unroll
  for (int f = 0; f < 8; ++f) acc[f] = (f32x4){0.f, 0.f, 0.f, 0.f};
  float dpart = 0.f;
  for (int s0 = sbeg; s0 < sbeg + 512; s0 += 32) {
    const int sk = s0 + kg * 8;
    f32x4 a0 = *(const f32x4*)(arow + sk);
    f32x4 a1 = *(const f32x4*)(arow + sk + 4);
    f32x4 sv0 = *(const f32x4*)(ssh + (sk - sbeg));
    f32x4 sv1 = *(const f32x4*)(ssh + (sk - sbeg) + 4);
    float av[8] = {a0[0], a0[1], a0[2], a0[3], a1[0], a1[1], a1[2], a1[3]};
    float sv[8] = {sv0[0], sv0[1], sv0[2], sv0[3],
                   sv1[0], sv1[1], sv1[2], sv1[3]};
    short pb[8];
#pragma unroll
    for (int j = 0; j < 8; ++j) {
      const int s = sk + j;
      const float a = av[j];
      const bool diag = (s == tRow);
      const float ev = diag ? ma_t : a;
      const bool adj = diag || (a > 0.f);
      float l = sv[j] + sd_t + ev * ce;
      l = fmaxf(l, NEG_SLOPE * l);
      const float pv = adj ? __expf(l) : 0.f;
      dpart += pv;
      pb[j] = f2bf(pv);
    }
    bf16x8 A = {pb[0], pb[1], pb[2], pb[3], pb[4], pb[5], pb[6], pb[7]};
    const __hip_bfloat16* bp = bbase + (size_t)s0 * 16;
#pragma unroll
    for (int f = 0; f < 8; ++f) {
      bf16x8 B = *(const bf16x8*)(bp + (size_t)f * (NN * 16));
      acc[f] = __builtin_amdgcn_mfma_f32_16x16x32_bf16(A, B, acc[f], 0, 0, 0);
    }
  }
  dpart += __shfl_xor(dpart, 16);
  dpart += __shfl_xor(dpart, 32);
  __syncthreads();
#pragma unroll
  for (int f = 0; f < 8; ++f)
#pragma unroll
    for (int r = 0; r < 4; ++r) red[w][kg * 4 + r][f * 16 + row] = acc[f][r];
  if (lane < 16) den_sh[w][lane] = dpart;
  __syncthreads();
#pragma unroll
  for (int i = 0; i < 8; ++i) {
    int idx = i * 256 + tid;
    int t = idx >> 7, c = idx & 127;
    float nsum = red[0][t][c] + red[1][t][c] + red[2][t][c] + red[3][t][c];
    float dsum = den_sh[0][t] + den_sh[1][t] + den_sh[2][t] + den_sh[3][t];
    float v = nsum / dsum + b1[h * 128 + c];
    feat1b[(size_t)(t0 + t) * 512 + h * 128 + c] =
        __float2bfloat16(v > 0.f ? v : 0.f);
  }
}

// ---------------------------------------------------------------------------
// K4 gemm2: h2 = feat1b @ W2 -> hTsw2 + fused ssrc2/sdst2. 128 blocks.
// ---------------------------------------------------------------------------
__global__ __launch_bounds__(256) void k_gemm2(
    const __hip_bfloat16* __restrict__ feat1b,
    const __hip_bfloat16* __restrict__ w2t, const float* __restrict__ asrc2,
    const float* __restrict__ adst2, __hip_bfloat16* __restrict__ hTsw2,
    float* __restrict__ ssrc2, float* __restrict__ sdst2) {
  const int tid = threadIdx.x;
  const int w = (int)blockIdx.x * 4 + (tid >> 6);  // 0..511
  const int lane = tid & 63, row = lane & 15, kg = lane >> 4;
  const int mb = w >> 2, nb = w & 3;
  const int m0 = mb * 16, n0 = nb * 32;
  const __hip_bfloat16* arow = feat1b + (size_t)(m0 + row) * 512 + kg * 8;
  f32x4 acc[2];
#pragma unroll
  for (int f = 0; f < 2; ++f) acc[f] = (f32x4){0.f, 0.f, 0.f, 0.f};
#pragma unroll
  for (int ks = 0; ks < 16; ++ks) {
    bf16x8 Af = *(const bf16x8*)(arow + ks * 32);
#pragma unroll
    for (int f = 0; f < 2; ++f) {
      bf16x8 Bf = *(const bf16x8*)(w2t + (size_t)(n0 + f * 16 + row) * 512 +
                                   kg * 8 + ks * 32);
      acc[f] = __builtin_amdgcn_mfma_f32_16x16x32_bf16(Af, Bf, acc[f], 0, 0, 0);
    }
  }
  float as[2], ad[2];
#pragma unroll
  for (int f = 0; f < 2; ++f) {
    int ch = (n0 + f * 16 + row) & 127;
    as[f] = asrc2[ch];
    ad[f] = adst2[ch];
  }
  float ps[4] = {0.f, 0.f, 0.f, 0.f}, pd[4] = {0.f, 0.f, 0.f, 0.f};
#pragma unroll
  for (int f = 0; f < 2; ++f)
#pragma unroll
    for (int r = 0; r < 4; ++r) {
      ps[r] += acc[f][r] * as[f];
      pd[r] += acc[f][r] * ad[f];
    }
#pragma unroll
  for (int m = 1; m < 16; m <<= 1) {
#pragma unroll
    for (int r = 0; r < 4; ++r) {
      ps[r] += __shfl_xor(ps[r], m);
      pd[r] += __shfl_xor(pd[r], m);
    }
  }
  if (row == 0) {
#pragma unroll
    for (int r = 0; r < 4; ++r) {
      int node = m0 + kg * 4 + r;
      atomicAdd(&ssrc2[node], ps[r]);
      atomicAdd(&sdst2[node], pd[r]);
    }
  }
#pragma unroll
  for (int f = 0; f < 2; ++f) {
    const int cbi = nb * 2 + f;
    short4 ct;
    ct.x = f2bf(acc[f][0]); ct.y = f2bf(acc[f][1]);
    ct.z = f2bf(acc[f][2]); ct.w = f2bf(acc[f][3]);
    size_t a4 = (size_t)cbi * (NN * 16) +
                (size_t)(((m0 >> 3) + (kg >> 1)) * 128 + row * 8 + (kg & 1) * 4);
    *(short4*)((short*)hTsw2 + a4) = ct;
  }
}

// ---------------------------------------------------------------------------
// K5 attn2 (1 head): 128 blocks x 16 targets; 4 waves = s-quarters; in-block
// stats; LDS reduce; write feat2 (fp32 + b2) directly.
// ---------------------------------------------------------------------------
__global__ __launch_bounds__(256) void k_attn2(
    const float* __restrict__ aggT, const __hip_bfloat16* __restrict__ hTsw2,
    const float* __restrict__ ssrc2, const float* __restrict__ sdst2,
    const float* __restrict__ ce_all, const float* __restrict__ b2,
    float* __restrict__ feat2) {
  const int tid = threadIdx.x;
  const int t0 = (int)blockIdx.x * 16;
  __shared__ float ss_sh[2048];
  __shared__ float red[4][16][128];
  __shared__ float den_sh[4][16];
  __shared__ float st_sum[4][16];
  __shared__ float st_cnt[4][16];
  for (int i = tid; i < 2048; i += 256) ss_sh[i] = ssrc2[i];
  __syncthreads();
  const int lane = tid & 63, w = tid >> 6, row = lane & 15, kg = lane >> 4;
  const int sbeg = w * 512;
  const int tRow = t0 + row;
  const float* arow = aggT + (size_t)tRow * NN;
  {
    float psum = 0.f, pcnt = 0.f;
    for (int s0 = sbeg; s0 < sbeg + 512; s0 += 32) {
      const int sk = s0 + kg * 8;
      f32x4 a0 = *(const f32x4*)(arow + sk);
      f32x4 a1 = *(const f32x4*)(arow + sk + 4);
      float av[8] = {a0[0], a0[1], a0[2], a0[3], a1[0], a1[1], a1[2], a1[3]};
#pragma unroll
      for (int j = 0; j < 8; ++j) {
        bool m = (av[j] > 0.f) && (sk + j != tRow);
        psum += m ? av[j] : 0.f;
        pcnt += m ? 1.f : 0.f;
      }
    }
    psum += __shfl_xor(psum, 16); psum += __shfl_xor(psum, 32);
    pcnt += __shfl_xor(pcnt, 16); pcnt += __shfl_xor(pcnt, 32);
    if (lane < 16) { st_sum[w][lane] = psum; st_cnt[w][lane] = pcnt; }
  }
  __syncthreads();
  const float ma_t =
      (st_sum[0][row] + st_sum[1][row] + st_sum[2][row] + st_sum[3][row]) /
      fmaxf(st_cnt[0][row] + st_cnt[1][row] + st_cnt[2][row] + st_cnt[3][row],
            1.f);
  const float ce = ce_all[4];
  const float sd_t = sdst2[tRow];
  const float* ssh = ss_sh + sbeg;
  const __hip_bfloat16* bbase = hTsw2 + kg * 128 + row * 8;
  f32x4 acc[8];
#pragma unroll
  for (int f = 0; f < 8; ++f) acc[f] = (f32x4){0.f, 0.f, 0.f, 0.f};
  float dpart = 0.f;
  for (int s0 = sbeg; s0 < sbeg + 512; s0 += 32) {
    const int sk = s0 + kg * 8;
    f32x4 a0 = *(const f32x4*)(arow + sk);
    f32x4 a1 = *(const f32x4*)(arow + sk + 4);
    f32x4 sv0 = *(const f32x4*)(ssh + (sk - sbeg));
    f32x4 sv1 = *(const f32x4*)(ssh + (sk - sbeg) + 4);
    float av[8] = {a0[0], a0[1], a0[2], a0[3], a1[0], a1[1], a1[2], a1[3]};
    float sv[8] = {sv0[0], sv0[1], sv0[2], sv0[3],
                   sv1[0], sv1[1], sv1[2], sv1[3]};
    short pb[8];
#pragma unroll
    for (int j = 0; j < 8; ++j) {
      const int s = sk + j;
      const float a = av[j];
      const bool diag = (s == tRow);
      const float ev = diag ? ma_t : a;
      const bool adj = diag || (a > 0.f);
      float l = sv[j] + sd_t + ev * ce;
      l = fmaxf(l, NEG_SLOPE * l);
      const float pv = adj ? __expf(l) : 0.f;
      dpart += pv;
      pb[j] = f2bf(pv);
    }
    bf16x8 A = {pb[0], pb[1], pb[2], pb[3], pb[4], pb[5], pb[6], pb[7]};
    const __hip_bfloat16* bp = bbase + (size_t)s0 * 16;
#pragma unroll
    for (int f = 0; f < 8; ++f) {
      bf16x8 B = *(const bf16x8*)(bp + (size_t)f * (NN * 16));
      acc[f] = __builtin_amdgcn_mfma_f32_16x16x32_bf16(A, B, acc[f], 0, 0, 0);
    }
  }
  dpart += __shfl_xor(dpart, 16);
  dpart += __shfl_xor(dpart, 32);
  __syncthreads();
#pragma unroll
  for (int f = 0; f < 8; ++f)
#pragma unroll
    for (int r = 0; r < 4; ++r) red[w][kg * 4 + r][f * 16 + row] = acc[f][r];
  if (lane < 16) den_sh[w][lane] = dpart;
  __syncthreads();
#pragma unroll
  for (int i = 0; i < 8; ++i) {
    int idx = i * 256 + tid;
    int t = idx >> 7, c = idx & 127;
    float nsum = red[0][t][c] + red[1][t][c] + red[2][t][c] + red[3][t][c];
    float dsum = den_sh[0][t] + den_sh[1][t] + den_sh[2][t] + den_sh[3][t];
    feat2[(size_t)(t0 + t) * 128 + c] = nsum / dsum + b2[c];
  }
}

// ---------------------------------------------------------------------------
// K6: segment mean pool + fc + log_softmax. 8 blocks x 256 threads.
// ---------------------------------------------------------------------------
__global__ __launch_bounds__(256) void k_poolhead(
    const float* __restrict__ feat, const int* __restrict__ bidx,
    const float* __restrict__ fcw, const float* __restrict__ fcb,
    float* __restrict__ out) {
  const int g = blockIdx.x;
  const int tid = threadIdx.x;
  __shared__ int lo[2];
  __shared__ float ps2[256];
  __shared__ float lsh[10];
  if (tid == 0) { lo[0] = NN; lo[1] = NN; }
  __syncthreads();
  for (int n = tid; n < NN; n += 256) {
    int b = bidx[n];
    int bprev = (n == 0) ? -1 : bidx[n - 1];
    if (b >= g && bprev < g) atomicMin(&lo[0], n);
    if (b >= g + 1 && bprev < g + 1) atomicMin(&lo[1], n);
  }
  __syncthreads();
  int s = lo[0], e = lo[1];
  const int c = tid & 127, half = tid >> 7;
  float sum = 0.f;
  for (int n = s + half; n < e; n += 2) sum += feat[(size_t)n * 128 + c];
  ps2[tid] = sum;
  __syncthreads();
  if (tid < 128) {
    float cntf = (float)((e - s) > 1 ? (e - s) : 1);
    ps2[tid] = (ps2[tid] + ps2[tid + 128]) / cntf;
  }
  __syncthreads();
  if (tid < 10) {
    float v = fcb[tid];
    for (int ch = 0; ch < 128; ++ch) v += ps2[ch] * fcw[ch * 10 + tid];
    lsh[tid] = v;
  }
  __syncthreads();
  if (tid < 10) {
    float m = -1e30f;
    for (int i = 0; i < 10; ++i) m = fmaxf(m, lsh[i]);
    float den = 0.f;
    for (int i = 0; i < 10; ++i) den += expf(lsh[i] - m);
    out[g * 10 + tid] = lsh[tid] - m - logf(den);
  }
}

extern "C" void kernel_launch(void* const* d_in, const int* in_sizes, int n_in,
                              void* d_out, int out_size, void* d_ws,
                              size_t ws_size, hipStream_t stream) {
  (void)in_sizes; (void)n_in; (void)out_size; (void)ws_size;
  const float* x      = (const float*)d_in[0];
  const float* attn   = (const float*)d_in[1];
  const int*   bidx   = (const int*)d_in[2];
  const float* conv_w = (const float*)d_in[3];
  const float* conv_b = (const float*)d_in[4];
  const float* W1     = (const float*)d_in[5];
  const float* asrc1  = (const float*)d_in[6];
  const float* adst1  = (const float*)d_in[7];
  const float* aedge1 = (const float*)d_in[8];
  const float* We1    = (const float*)d_in[9];
  const float* b1     = (const float*)d_in[10];
  const float* W2     = (const float*)d_in[11];
  const float* asrc2  = (const float*)d_in[12];
  const float* adst2  = (const float*)d_in[13];
  const float* aedge2 = (const float*)d_in[14];
  const float* We2    = (const float*)d_in[15];
  const float* b2     = (const float*)d_in[16];
  const float* fcw    = (const float*)d_in[17];
  const float* fcb    = (const float*)d_in[18];

  float* ws = (float*)d_ws;
  float* aggT  = ws;                    // 4,194,304
  float* feat2 = aggT + 4194304;        //   262,144
  float* ssrc1 = feat2 + 262144;        //     8,192  <- zero region (20480)
  float* sdst1 = ssrc1 + 8192;          //     8,192
  float* ssrc2 = sdst1 + 8192;          //     2,048
  float* sdst2 = ssrc2 + 2048;          //     2,048
  float* ce    = sdst2 + 2048;          //        64
  float* bf    = ce + 64;
  __hip_bfloat16* w1t    = (__hip_bfloat16*)bf;             //    65,536 el
  __hip_bfloat16* w2t    = (__hip_bfloat16*)(bf + 32768);   //    65,536 el
  __hip_bfloat16* hTsw1  = (__hip_bfloat16*)(bf + 65536);   // 1,048,576 el
  __hip_bfloat16* hTsw2  = (__hip_bfloat16*)(bf + 589824);  //   262,144 el
  __hip_bfloat16* feat1b = (__hip_bfloat16*)(bf + 720896);  // 1,048,576 el

  k_pre<<<1109, 256, 0, stream>>>(attn, conv_w, conv_b, W1, W2, aedge1, We1,
                                  aedge2, We2, aggT, w1t, w2t, ssrc1, ce);
  k_gemm1<<<512, 256, 0, stream>>>(x, w1t, asrc1, adst1, hTsw1, ssrc1, sdst1);
  k_attn1<<<512, 256, 0, stream>>>(aggT, hTsw1, ssrc1, sdst1, ce, b1, feat1b);
  k_gemm2<<<128, 256, 0, stream>>>(feat1b, w2t, asrc2, adst2, hTsw2, ssrc2,
                                   sdst2);
  k_attn2<<<128, 256, 0, stream>>>(aggT, hTsw2, ssrc2, sdst2, ce, b2, feat2);
  k_poolhead<<<8, 256, 0, stream>>>(feat2, bidx, fcw, fcb, (float*)d_out);
}

// Round 9
// 133.290 us; speedup vs baseline: 7.0539x; 1.1076x over previous
//
#include <hip/hip_runtime.h>
#include <hip/hip_bf16.h>
#include <math.h>

#define NN 2048
#define NEG_SLOPE 0.2f

typedef __attribute__((ext_vector_type(8))) short bf16x8;
typedef __attribute__((ext_vector_type(4))) float f32x4;

static __device__ inline short f2bf(float x) {
  union { float f; unsigned u; } v;
  v.f = x;
  unsigned r = v.u + 0x7fffu + ((v.u >> 16) & 1u);  // RNE
  return (short)(r >> 16);
}

// ---------------------------------------------------------------------------
// K1 k_pre: blocks 0-1023: conv -> aggT (64x64 tile, LDS transpose) + masked
// column-stat partials (non-atomic, owned by (s-block,t)). 1024-1055: w1t.
// 1056-1087: w2t. 1088: ce.
// ---------------------------------------------------------------------------
__global__ __launch_bounds__(256) void k_pre(
    const float* __restrict__ attn, const float* __restrict__ conv_w,
    const float* __restrict__ conv_b, const float* __restrict__ W1,
    const float* __restrict__ W2, const float* __restrict__ ae1,
    const float* __restrict__ We1, const float* __restrict__ ae2,
    const float* __restrict__ We2, float* __restrict__ aggT,
    float* __restrict__ ssum_part, float* __restrict__ scnt_part,
    __hip_bfloat16* __restrict__ w1t, __hip_bfloat16* __restrict__ w2t,
    float* __restrict__ ce) {
  const int b = blockIdx.x;
  const int tid = threadIdx.x;
  if (b < 1024) {
    __shared__ float tile[64][68];
    const int t0 = (b & 31) * 64;
    const int s0 = (b >> 5) * 64;
    const int sl = tid >> 4;           // 0..15 (s within tile, +16k)
    const int t4 = (tid & 15) * 4;     // t quad
    float w[12];
#pragma unroll
    for (int c = 0; c < 12; ++c) w[c] = conv_w[c];
    const float cb = conv_b[0];
    f32x4 acc[4];
#pragma unroll
    for (int k = 0; k < 4; ++k) acc[k] = (f32x4){cb, cb, cb, cb};
    for (int c = 0; c < 12; ++c) {
      const float* base =
          attn + (size_t)c * NN * NN + (size_t)(s0 + sl) * NN + t0 + t4;
#pragma unroll
      for (int k = 0; k < 4; ++k)
        acc[k] += w[c] * *(const f32x4*)(base + (size_t)k * 16 * NN);
    }
#pragma unroll
    for (int k = 0; k < 4; ++k) *(f32x4*)&tile[sl + 16 * k][t4] = acc[k];
    __syncthreads();
    const int tl = tid >> 2;           // 0..63 (t row)
    const int sq = (tid & 3) * 16;     // s quad-of-16
    const int tglob = t0 + tl;
    float* orow = aggT + (size_t)tglob * NN + s0 + sq;
    float psum = 0.f, pcnt = 0.f;
#pragma unroll
    for (int g = 0; g < 4; ++g) {
      f32x4 v = {tile[sq + 4 * g][tl], tile[sq + 4 * g + 1][tl],
                 tile[sq + 4 * g + 2][tl], tile[sq + 4 * g + 3][tl]};
      *(f32x4*)(orow + 4 * g) = v;
#pragma unroll
      for (int j = 0; j < 4; ++j) {
        int sglob = s0 + sq + 4 * g + j;
        bool m = (v[j] > 0.f) && (sglob != tglob);
        psum += m ? v[j] : 0.f;
        pcnt += m ? 1.f : 0.f;
      }
    }
    psum += __shfl_down(psum, 1); psum += __shfl_down(psum, 2);
    pcnt += __shfl_down(pcnt, 1); pcnt += __shfl_down(pcnt, 2);
    if ((tid & 3) == 0) {
      ssum_part[(b >> 5) * NN + tglob] = psum;
      scnt_part[(b >> 5) * NN + tglob] = pcnt;
    }
  } else if (b < 1056) {
#pragma unroll
    for (int k = 0; k < 8; ++k) {
      int o = (b - 1024) * 2048 + k * 256 + tid;
      ((short*)w1t)[o] = f2bf(W1[(o & 127) * 512 + (o >> 7)]);
    }
  } else if (b < 1088) {
#pragma unroll
    for (int k = 0; k < 8; ++k) {
      int o = (b - 1056) * 2048 + k * 256 + tid;
      ((short*)w2t)[o] = f2bf(W2[(o & 511) * 128 + (o >> 9)]);
    }
  } else {
    const int lane = tid & 63;
    const int wv = tid >> 6;
    float q1 = ae1[wv * 128 + lane] * We1[wv * 128 + lane] +
               ae1[wv * 128 + 64 + lane] * We1[wv * 128 + 64 + lane];
    for (int off = 32; off; off >>= 1) q1 += __shfl_down(q1, off);
    if (lane == 0) ce[wv] = q1;
    float q2 = ae2[lane] * We2[lane] + ae2[64 + lane] * We2[64 + lane];
    for (int off = 32; off; off >>= 1) q2 += __shfl_down(q2, off);
    if (tid == 0) ce[4] = q2;
  }
}

// ---------------------------------------------------------------------------
// K2 gemm1: h1 = x @ W1 (A converted fp32->bf16 in-reg) -> swizzled hTsw1
// + ssrc/sdst PARTIALS (slot nb, non-atomic). 512 blocks x 4 waves.
// ---------------------------------------------------------------------------
__global__ __launch_bounds__(256) void k_gemm1(
    const float* __restrict__ x, const __hip_bfloat16* __restrict__ w1t,
    const float* __restrict__ asrc1, const float* __restrict__ adst1,
    __hip_bfloat16* __restrict__ hTsw1, float* __restrict__ sspart1,
    float* __restrict__ sdpart1) {
  const int tid = threadIdx.x;
  const int w = (int)blockIdx.x * 4 + (tid >> 6);  // 0..2047
  const int lane = tid & 63, row = lane & 15, kg = lane >> 4;
  const int mb = w >> 4, nb = w & 15;
  const int m0 = mb * 16, n0 = nb * 32;
  const float* axrow = x + (size_t)(m0 + row) * 128 + kg * 8;
  f32x4 acc[2];
#pragma unroll
  for (int f = 0; f < 2; ++f) acc[f] = (f32x4){0.f, 0.f, 0.f, 0.f};
#pragma unroll
  for (int ks = 0; ks < 4; ++ks) {
    f32x4 xa = *(const f32x4*)(axrow + ks * 32);
    f32x4 xb = *(const f32x4*)(axrow + ks * 32 + 4);
    bf16x8 Af = {f2bf(xa[0]), f2bf(xa[1]), f2bf(xa[2]), f2bf(xa[3]),
                 f2bf(xb[0]), f2bf(xb[1]), f2bf(xb[2]), f2bf(xb[3])};
#pragma unroll
    for (int f = 0; f < 2; ++f) {
      bf16x8 Bf = *(const bf16x8*)(w1t + (size_t)(n0 + f * 16 + row) * 128 +
                                   kg * 8 + ks * 32);
      acc[f] = __builtin_amdgcn_mfma_f32_16x16x32_bf16(Af, Bf, acc[f], 0, 0, 0);
    }
  }
  const int h = nb >> 2;
  float as[2], ad[2];
#pragma unroll
  for (int f = 0; f < 2; ++f) {
    int ch = (n0 + f * 16 + row) & 127;
    as[f] = asrc1[h * 128 + ch];
    ad[f] = adst1[h * 128 + ch];
  }
  float ps[4] = {0.f, 0.f, 0.f, 0.f}, pd[4] = {0.f, 0.f, 0.f, 0.f};
#pragma unroll
  for (int f = 0; f < 2; ++f)
#pragma unroll
    for (int r = 0; r < 4; ++r) {
      ps[r] += acc[f][r] * as[f];
      pd[r] += acc[f][r] * ad[f];
    }
#pragma unroll
  for (int m = 1; m < 16; m <<= 1) {
#pragma unroll
    for (int r = 0; r < 4; ++r) {
      ps[r] += __shfl_xor(ps[r], m);
      pd[r] += __shfl_xor(pd[r], m);
    }
  }
  if (row == 0) {
#pragma unroll
    for (int r = 0; r < 4; ++r) {
      int node = m0 + kg * 4 + r;
      sspart1[nb * NN + node] = ps[r];
      sdpart1[nb * NN + node] = pd[r];
    }
  }
#pragma unroll
  for (int f = 0; f < 2; ++f) {
    const int cbi = nb * 2 + f;
    short4 ct;
    ct.x = f2bf(acc[f][0]); ct.y = f2bf(acc[f][1]);
    ct.z = f2bf(acc[f][2]); ct.w = f2bf(acc[f][3]);
    size_t a4 = (size_t)cbi * (NN * 16) +
                (size_t)(((m0 >> 3) + (kg >> 1)) * 128 + row * 8 + (kg & 1) * 4);
    *(short4*)((short*)hTsw1 + a4) = ct;
  }
}

// ---------------------------------------------------------------------------
// K3 attn1: 512 blocks = 128 t-tiles x 4 heads; 4 waves = 4 s-quarters.
// mean_attr from k_pre partials (no aggT stats pass). LDS reduce across
// waves; write feat1b (bias+ReLU+bf16) directly.
// ---------------------------------------------------------------------------
__global__ __launch_bounds__(256) void k_attn1(
    const float* __restrict__ aggT, const __hip_bfloat16* __restrict__ hTsw1,
    const float* __restrict__ sspart1, const float* __restrict__ sdpart1,
    const float* __restrict__ ssum_part, const float* __restrict__ scnt_part,
    const float* __restrict__ ce_all, const float* __restrict__ b1,
    __hip_bfloat16* __restrict__ feat1b) {
  const int tid = threadIdx.x;
  const int t0 = (int)(blockIdx.x >> 2) * 16;
  const int h = (int)(blockIdx.x & 3u);
  __shared__ float ss_sh[2048];
  __shared__ float red[4][16][128];
  __shared__ float den_sh[4][16];
  for (int i = tid; i < 2048; i += 256)
    ss_sh[i] = sspart1[(4 * h + 0) * NN + i] + sspart1[(4 * h + 1) * NN + i] +
               sspart1[(4 * h + 2) * NN + i] + sspart1[(4 * h + 3) * NN + i];
  __syncthreads();
  const int lane = tid & 63, w = tid >> 6, row = lane & 15, kg = lane >> 4;
  const int sbeg = w * 512;
  const int tRow = t0 + row;
  const float* arow = aggT + (size_t)tRow * NN;
  float msum = 0.f, mcnt = 0.f;
#pragma unroll
  for (int q = 0; q < 32; ++q) {
    msum += ssum_part[q * NN + tRow];
    mcnt += scnt_part[q * NN + tRow];
  }
  const float ma_t = msum / fmaxf(mcnt, 1.f);
  const float ce = ce_all[h];
  const float sd_t = sdpart1[(4 * h + 0) * NN + tRow] +
                     sdpart1[(4 * h + 1) * NN + tRow] +
                     sdpart1[(4 * h + 2) * NN + tRow] +
                     sdpart1[(4 * h + 3) * NN + tRow];
  const float* ssh = ss_sh + sbeg;
  const __hip_bfloat16* bbase =
      hTsw1 + (size_t)(h * 8) * (NN * 16) + kg * 128 + row * 8;
  f32x4 acc[8];
#pragma unroll
  for (int f = 0; f < 8; ++f) acc[f] = (f32x4){0.f, 0.f, 0.f, 0.f};
  float dpart = 0.f;
  for (int s0 = sbeg; s0 < sbeg + 512; s0 += 32) {
    const int sk = s0 + kg * 8;
    f32x4 a0 = *(const f32x4*)(arow + sk);
    f32x4 a1 = *(const f32x4*)(arow + sk + 4);
    f32x4 sv0 = *(const f32x4*)(ssh + (sk - sbeg));
    f32x4 sv1 = *(const f32x4*)(ssh + (sk - sbeg) + 4);
    float av[8] = {a0[0], a0[1], a0[2], a0[3], a1[0], a1[1], a1[2], a1[3]};
    float sv[8] = {sv0[0], sv0[1], sv0[2], sv0[3],
                   sv1[0], sv1[1], sv1[2], sv1[3]};
    short pb[8];
#pragma unroll
    for (int j = 0; j < 8; ++j) {
      const int s = sk + j;
      const float a = av[j];
      const bool diag = (s == tRow);
      const float ev = diag ? ma_t : a;
      const bool adj = diag || (a > 0.f);
      float l = sv[j] + sd_t + ev * ce;
      l = fmaxf(l, NEG_SLOPE * l);
      const float pv = adj ? __expf(l) : 0.f;
      dpart += pv;
      pb[j] = f2bf(pv);
    }
    bf16x8 A = {pb[0], pb[1], pb[2], pb[3], pb[4], pb[5], pb[6], pb[7]};
    const __hip_bfloat16* bp = bbase + (size_t)s0 * 16;
#pragma unroll
    for (int f = 0; f < 8; ++f) {
      bf16x8 B = *(const bf16x8*)(bp + (size_t)f * (NN * 16));
      acc[f] = __builtin_amdgcn_mfma_f32_16x16x32_bf16(A, B, acc[f], 0, 0, 0);
    }
  }
  dpart += __shfl_xor(dpart, 16);
  dpart += __shfl_xor(dpart, 32);
  __syncthreads();
#pragma unroll
  for (int f = 0; f < 8; ++f)
#pragma unroll
    for (int r = 0; r < 4; ++r) red[w][kg * 4 + r][f * 16 + row] = acc[f][r];
  if (lane < 16) den_sh[w][lane] = dpart;
  __syncthreads();
#pragma unroll
  for (int i = 0; i < 8; ++i) {
    int idx = i * 256 + tid;
    int t = idx >> 7, c = idx & 127;
    float nsum = red[0][t][c] + red[1][t][c] + red[2][t][c] + red[3][t][c];
    float dsum = den_sh[0][t] + den_sh[1][t] + den_sh[2][t] + den_sh[3][t];
    float v = nsum / dsum + b1[h * 128 + c];
    feat1b[(size_t)(t0 + t) * 512 + h * 128 + c] =
        __float2bfloat16(v > 0.f ? v : 0.f);
  }
}

// ---------------------------------------------------------------------------
// K4 gemm2: h2 = feat1b @ W2 -> hTsw2; ssrc2/sdst2 via LDS cross-wave reduce
// (block owns its 16 nodes -> direct non-atomic write). 128 blocks.
// ---------------------------------------------------------------------------
__global__ __launch_bounds__(256) void k_gemm2(
    const __hip_bfloat16* __restrict__ feat1b,
    const __hip_bfloat16* __restrict__ w2t, const float* __restrict__ asrc2,
    const float* __restrict__ adst2, __hip_bfloat16* __restrict__ hTsw2,
    float* __restrict__ ssrc2, float* __restrict__ sdst2) {
  const int tid = threadIdx.x;
  const int wv = tid >> 6;
  const int w = (int)blockIdx.x * 4 + wv;  // 0..511
  const int lane = tid & 63, row = lane & 15, kg = lane >> 4;
  const int mb = w >> 2, nb = w & 3;
  const int m0 = mb * 16, n0 = nb * 32;
  __shared__ float sred[2][4][16];
  const __hip_bfloat16* arow = feat1b + (size_t)(m0 + row) * 512 + kg * 8;
  f32x4 acc[2];
#pragma unroll
  for (int f = 0; f < 2; ++f) acc[f] = (f32x4){0.f, 0.f, 0.f, 0.f};
#pragma unroll
  for (int ks = 0; ks < 16; ++ks) {
    bf16x8 Af = *(const bf16x8*)(arow + ks * 32);
#pragma unroll
    for (int f = 0; f < 2; ++f) {
      bf16x8 Bf = *(const bf16x8*)(w2t + (size_t)(n0 + f * 16 + row) * 512 +
                                   kg * 8 + ks * 32);
      acc[f] = __builtin_amdgcn_mfma_f32_16x16x32_bf16(Af, Bf, acc[f], 0, 0, 0);
    }
  }
  float as[2], ad[2];
#pragma unroll
  for (int f = 0; f < 2; ++f) {
    int ch = (n0 + f * 16 + row) & 127;
    as[f] = asrc2[ch];
    ad[f] = adst2[ch];
  }
  float ps[4] = {0.f, 0.f, 0.f, 0.f}, pd[4] = {0.f, 0.f, 0.f, 0.f};
#pragma unroll
  for (int f = 0; f < 2; ++f)
#pragma unroll
    for (int r = 0; r < 4; ++r) {
      ps[r] += acc[f][r] * as[f];
      pd[r] += acc[f][r] * ad[f];
    }
#pragma unroll
  for (int m = 1; m < 16; m <<= 1) {
#pragma unroll
    for (int r = 0; r < 4; ++r) {
      ps[r] += __shfl_xor(ps[r], m);
      pd[r] += __shfl_xor(pd[r], m);
    }
  }
  if (row == 0) {
#pragma unroll
    for (int r = 0; r < 4; ++r) {
      sred[0][wv][kg * 4 + r] = ps[r];
      sred[1][wv][kg * 4 + r] = pd[r];
    }
  }
  __syncthreads();
  if (tid < 16) {
    float s = sred[0][0][tid] + sred[0][1][tid] + sred[0][2][tid] +
              sred[0][3][tid];
    float d = sred[1][0][tid] + sred[1][1][tid] + sred[1][2][tid] +
              sred[1][3][tid];
    ssrc2[(int)blockIdx.x * 16 + tid] = s;
    sdst2[(int)blockIdx.x * 16 + tid] = d;
  }
#pragma unroll
  for (int f = 0; f < 2; ++f) {
    const int cbi = nb * 2 + f;
    short4 ct;
    ct.x = f2bf(acc[f][0]); ct.y = f2bf(acc[f][1]);
    ct.z = f2bf(acc[f][2]); ct.w = f2bf(acc[f][3]);
    size_t a4 = (size_t)cbi * (NN * 16) +
                (size_t)(((m0 >> 3) + (kg >> 1)) * 128 + row * 8 + (kg & 1) * 4);
    *(short4*)((short*)hTsw2 + a4) = ct;
  }
}

// ---------------------------------------------------------------------------
// K5 attn2 (1 head): 256 blocks = 128 t-tiles x 2 col-halves; 4 waves =
// s-quarters; mean from partials; LDS reduce; write feat2 directly.
// ---------------------------------------------------------------------------
__global__ __launch_bounds__(256) void k_attn2(
    const float* __restrict__ aggT, const __hip_bfloat16* __restrict__ hTsw2,
    const float* __restrict__ ssrc2, const float* __restrict__ sdst2,
    const float* __restrict__ ssum_part, const float* __restrict__ scnt_part,
    const float* __restrict__ ce_all, const float* __restrict__ b2,
    float* __restrict__ feat2) {
  const int tid = threadIdx.x;
  const int t0 = (int)(blockIdx.x >> 1) * 16;
  const int chalf = (int)(blockIdx.x & 1u);
  __shared__ float ss_sh[2048];
  __shared__ float red[4][16][64];
  __shared__ float den_sh[4][16];
  for (int i = tid; i < 2048; i += 256) ss_sh[i] = ssrc2[i];
  __syncthreads();
  const int lane = tid & 63, w = tid >> 6, row = lane & 15, kg = lane >> 4;
  const int sbeg = w * 512;
  const int tRow = t0 + row;
  const float* arow = aggT + (size_t)tRow * NN;
  float msum = 0.f, mcnt = 0.f;
#pragma unroll
  for (int q = 0; q < 32; ++q) {
    msum += ssum_part[q * NN + tRow];
    mcnt += scnt_part[q * NN + tRow];
  }
  const float ma_t = msum / fmaxf(mcnt, 1.f);
  const float ce = ce_all[4];
  const float sd_t = sdst2[tRow];
  const float* ssh = ss_sh + sbeg;
  const __hip_bfloat16* bbase =
      hTsw2 + (size_t)(chalf * 4) * (NN * 16) + kg * 128 + row * 8;
  f32x4 acc[4];
#pragma unroll
  for (int f = 0; f < 4; ++f) acc[f] = (f32x4){0.f, 0.f, 0.f, 0.f};
  float dpart = 0.f;
  for (int s0 = sbeg; s0 < sbeg + 512; s0 += 32) {
    const int sk = s0 + kg * 8;
    f32x4 a0 = *(const f32x4*)(arow + sk);
    f32x4 a1 = *(const f32x4*)(arow + sk + 4);
    f32x4 sv0 = *(const f32x4*)(ssh + (sk - sbeg));
    f32x4 sv1 = *(const f32x4*)(ssh + (sk - sbeg) + 4);
    float av[8] = {a0[0], a0[1], a0[2], a0[3], a1[0], a1[1], a1[2], a1[3]};
    float sv[8] = {sv0[0], sv0[1], sv0[2], sv0[3],
                   sv1[0], sv1[1], sv1[2], sv1[3]};
    short pb[8];
#pragma unroll
    for (int j = 0; j < 8; ++j) {
      const int s = sk + j;
      const float a = av[j];
      const bool diag = (s == tRow);
      const float ev = diag ? ma_t : a;
      const bool adj = diag || (a > 0.f);
      float l = sv[j] + sd_t + ev * ce;
      l = fmaxf(l, NEG_SLOPE * l);
      const float pv = adj ? __expf(l) : 0.f;
      dpart += pv;
      pb[j] = f2bf(pv);
    }
    bf16x8 A = {pb[0], pb[1], pb[2], pb[3], pb[4], pb[5], pb[6], pb[7]};
    const __hip_bfloat16* bp = bbase + (size_t)s0 * 16;
#pragma unroll
    for (int f = 0; f < 4; ++f) {
      bf16x8 B = *(const bf16x8*)(bp + (size_t)f * (NN * 16));
      acc[f] = __builtin_amdgcn_mfma_f32_16x16x32_bf16(A, B, acc[f], 0, 0, 0);
    }
  }
  dpart += __shfl_xor(dpart, 16);
  dpart += __shfl_xor(dpart, 32);
  __syncthreads();
#pragma unroll
  for (int f = 0; f < 4; ++f)
#pragma unroll
    for (int r = 0; r < 4; ++r) red[w][kg * 4 + r][f * 16 + row] = acc[f][r];
  if (lane < 16) den_sh[w][lane] = dpart;
  __syncthreads();
#pragma unroll
  for (int i = 0; i < 4; ++i) {
    int idx = i * 256 + tid;
    int t = idx >> 6, c = idx & 63;
    float nsum = red[0][t][c] + red[1][t][c] + red[2][t][c] + red[3][t][c];
    float dsum = den_sh[0][t] + den_sh[1][t] + den_sh[2][t] + den_sh[3][t];
    feat2[(size_t)(t0 + t) * 128 + chalf * 64 + c] =
        nsum / dsum + b2[chalf * 64 + c];
  }
}

// ---------------------------------------------------------------------------
// K6: segment mean pool + fc + log_softmax. 8 blocks x 256 threads.
// ---------------------------------------------------------------------------
__global__ __launch_bounds__(256) void k_poolhead(
    const float* __restrict__ feat, const int* __restrict__ bidx,
    const float* __restrict__ fcw, const float* __restrict__ fcb,
    float* __restrict__ out) {
  const int g = blockIdx.x;
  const int tid = threadIdx.x;
  __shared__ int lo[2];
  __shared__ float ps2[256];
  __shared__ float lsh[10];
  if (tid == 0) { lo[0] = NN; lo[1] = NN; }
  __syncthreads();
  for (int n = tid; n < NN; n += 256) {
    int b = bidx[n];
    int bprev = (n == 0) ? -1 : bidx[n - 1];
    if (b >= g && bprev < g) atomicMin(&lo[0], n);
    if (b >= g + 1 && bprev < g + 1) atomicMin(&lo[1], n);
  }
  __syncthreads();
  int s = lo[0], e = lo[1];
  const int c = tid & 127, half = tid >> 7;
  float sum = 0.f;
  for (int n = s + half; n < e; n += 2) sum += feat[(size_t)n * 128 + c];
  ps2[tid] = sum;
  __syncthreads();
  if (tid < 128) {
    float cntf = (float)((e - s) > 1 ? (e - s) : 1);
    ps2[tid] = (ps2[tid] + ps2[tid + 128]) / cntf;
  }
  __syncthreads();
  if (tid < 10) {
    float v = fcb[tid];
    for (int ch = 0; ch < 128; ++ch) v += ps2[ch] * fcw[ch * 10 + tid];
    lsh[tid] = v;
  }
  __syncthreads();
  if (tid < 10) {
    float m = -1e30f;
    for (int i = 0; i < 10; ++i) m = fmaxf(m, lsh[i]);
    float den = 0.f;
    for (int i = 0; i < 10; ++i) den += expf(lsh[i] - m);
    out[g * 10 + tid] = lsh[tid] - m - logf(den);
  }
}

extern "C" void kernel_launch(void* const* d_in, const int* in_sizes, int n_in,
                              void* d_out, int out_size, void* d_ws,
                              size_t ws_size, hipStream_t stream) {
  (void)in_sizes; (void)n_in; (void)out_size; (void)ws_size;
  const float* x      = (const float*)d_in[0];
  const float* attn   = (const float*)d_in[1];
  const int*   bidx   = (const int*)d_in[2];
  const float* conv_w = (const float*)d_in[3];
  const float* conv_b = (const float*)d_in[4];
  const float* W1     = (const float*)d_in[5];
  const float* asrc1  = (const float*)d_in[6];
  const float* adst1  = (const float*)d_in[7];
  const float* aedge1 = (const float*)d_in[8];
  const float* We1    = (const float*)d_in[9];
  const float* b1     = (const float*)d_in[10];
  const float* W2     = (const float*)d_in[11];
  const float* asrc2  = (const float*)d_in[12];
  const float* adst2  = (const float*)d_in[13];
  const float* aedge2 = (const float*)d_in[14];
  const float* We2    = (const float*)d_in[15];
  const float* b2     = (const float*)d_in[16];
  const float* fcw    = (const float*)d_in[17];
  const float* fcb    = (const float*)d_in[18];

  float* ws = (float*)d_ws;
  float* aggT      = ws;                   // 4,194,304
  float* feat2     = aggT + 4194304;       //   262,144
  float* ssum_part = feat2 + 262144;       //    65,536 (32 x 2048)
  float* scnt_part = ssum_part + 65536;    //    65,536
  float* sspart1   = scnt_part + 65536;    //    32,768 (16 x 2048)
  float* sdpart1   = sspart1 + 32768;      //    32,768
  float* ssrc2     = sdpart1 + 32768;      //     2,048
  float* sdst2     = ssrc2 + 2048;         //     2,048
  float* ce        = sdst2 + 2048;         //        64
  float* bf        = ce + 64;
  __hip_bfloat16* w1t    = (__hip_bfloat16*)bf;             //    65,536 el
  __hip_bfloat16* w2t    = (__hip_bfloat16*)(bf + 32768);   //    65,536 el
  __hip_bfloat16* hTsw1  = (__hip_bfloat16*)(bf + 65536);   // 1,048,576 el
  __hip_bfloat16* hTsw2  = (__hip_bfloat16*)(bf + 589824);  //   262,144 el
  __hip_bfloat16* feat1b = (__hip_bfloat16*)(bf + 720896);  // 1,048,576 el

  k_pre<<<1089, 256, 0, stream>>>(attn, conv_w, conv_b, W1, W2, aedge1, We1,
                                  aedge2, We2, aggT, ssum_part, scnt_part, w1t,
                                  w2t, ce);
  k_gemm1<<<512, 256, 0, stream>>>(x, w1t, asrc1, adst1, hTsw1, sspart1,
                                   sdpart1);
  k_attn1<<<512, 256, 0, stream>>>(aggT, hTsw1, sspart1, sdpart1, ssum_part,
                                   scnt_part, ce, b1, feat1b);
  k_gemm2<<<128, 256, 0, stream>>>(feat1b, w2t, asrc2, adst2, hTsw2, ssrc2,
                                   sdst2);
  k_attn2<<<256, 256, 0, stream>>>(aggT, hTsw2, ssrc2, sdst2, ssum_part,
                                   scnt_part, ce, b2, feat2);
  k_poolhead<<<8, 256, 0, stream>>>(feat2, bidx, fcw, fcb, (float*)d_out);
}

// Round 11
// 131.771 us; speedup vs baseline: 7.1352x; 1.0115x over previous
//
#include <hip/hip_runtime.h>
#include <hip/hip_bf16.h>
#include <math.h>

#define NN 2048
#define NEG_SLOPE 0.2f

typedef __attribute__((ext_vector_type(8))) short bf16x8;
typedef __attribute__((ext_vector_type(4))) float f32x4;

static __device__ inline short f2bf(float x) {
  union { float f; unsigned u; } v;
  v.f = x;
  unsigned r = v.u + 0x7fffu + ((v.u >> 16) & 1u);  // RNE
  return (short)(r >> 16);
}

// ---------------------------------------------------------------------------
// K1 k_pre: blocks 0-511: gemm1 (x @ W1, W1 staged per-block via LDS
// transpose+bf16 BIT store) -> swizzled hTsw1 + ssrc/sdst partials.
// Blocks 512-1535: conv -> aggT (64x64 tile, LDS transpose) + stat partials.
// 1536-1567: w2t. 1568: ce. gemm1 first so MFMA overlaps memory-bound conv.
// ---------------------------------------------------------------------------
__global__ __launch_bounds__(256) void k_pre(
    const float* __restrict__ attn, const float* __restrict__ conv_w,
    const float* __restrict__ conv_b, const float* __restrict__ x,
    const float* __restrict__ W1, const float* __restrict__ W2,
    const float* __restrict__ asrc1, const float* __restrict__ adst1,
    const float* __restrict__ ae1, const float* __restrict__ We1,
    const float* __restrict__ ae2, const float* __restrict__ We2,
    float* __restrict__ aggT, float* __restrict__ ssum_part,
    float* __restrict__ scnt_part, __hip_bfloat16* __restrict__ hTsw1,
    float* __restrict__ sspart1, float* __restrict__ sdpart1,
    __hip_bfloat16* __restrict__ w2t, float* __restrict__ ce) {
  const int b = blockIdx.x;
  const int tid = threadIdx.x;
  __shared__ __align__(16) char smem[34816];
  if (b < 512) {
    // ---------------- gemm1 ----------------
    typedef short w1row[136];       // 136 shorts = 272 B (16B-aligned rows)
    w1row* w1s = (w1row*)smem;      // [128 cols][136 k] bf16 bits
    const int mb = b >> 2, cblk = b & 3;
    const int m0 = mb * 16;
    // stage W1[k][cblk*128 + c] -> w1s[c][k]  (bit store, NOT numeric ctor)
    for (int e = tid; e < 128 * 32; e += 256) {
      int k = e >> 5, cq = (e & 31) * 4;
      f32x4 v = *(const f32x4*)(W1 + (size_t)k * 512 + cblk * 128 + cq);
#pragma unroll
      for (int j = 0; j < 4; ++j) w1s[cq + j][k] = f2bf(v[j]);
    }
    __syncthreads();
    const int wv = tid >> 6;
    const int lane = tid & 63, row = lane & 15, kg = lane >> 4;
    const int nb = cblk * 4 + wv;       // 0..15
    const int n0l = wv * 32;            // col base within this block's 128
    const float* axrow = x + (size_t)(m0 + row) * 128 + kg * 8;
    f32x4 acc[2];
#pragma unroll
    for (int f = 0; f < 2; ++f) acc[f] = (f32x4){0.f, 0.f, 0.f, 0.f};
#pragma unroll
    for (int ks = 0; ks < 4; ++ks) {
      f32x4 xa = *(const f32x4*)(axrow + ks * 32);
      f32x4 xb = *(const f32x4*)(axrow + ks * 32 + 4);
      bf16x8 Af = {f2bf(xa[0]), f2bf(xa[1]), f2bf(xa[2]), f2bf(xa[3]),
                   f2bf(xb[0]), f2bf(xb[1]), f2bf(xb[2]), f2bf(xb[3])};
#pragma unroll
      for (int f = 0; f < 2; ++f) {
        bf16x8 Bf = *(const bf16x8*)&w1s[n0l + f * 16 + row][kg * 8 + ks * 32];
        acc[f] =
            __builtin_amdgcn_mfma_f32_16x16x32_bf16(Af, Bf, acc[f], 0, 0, 0);
      }
    }
    const int h = nb >> 2;
    float as[2], ad[2];
#pragma unroll
    for (int f = 0; f < 2; ++f) {
      int ch = (n0l + f * 16 + row) & 127;
      as[f] = asrc1[h * 128 + ch];
      ad[f] = adst1[h * 128 + ch];
    }
    float ps[4] = {0.f, 0.f, 0.f, 0.f}, pd[4] = {0.f, 0.f, 0.f, 0.f};
#pragma unroll
    for (int f = 0; f < 2; ++f)
#pragma unroll
      for (int r = 0; r < 4; ++r) {
        ps[r] += acc[f][r] * as[f];
        pd[r] += acc[f][r] * ad[f];
      }
#pragma unroll
    for (int m = 1; m < 16; m <<= 1) {
#pragma unroll
      for (int r = 0; r < 4; ++r) {
        ps[r] += __shfl_xor(ps[r], m);
        pd[r] += __shfl_xor(pd[r], m);
      }
    }
    if (row == 0) {
#pragma unroll
      for (int r = 0; r < 4; ++r) {
        int node = m0 + kg * 4 + r;
        sspart1[nb * NN + node] = ps[r];
        sdpart1[nb * NN + node] = pd[r];
      }
    }
#pragma unroll
    for (int f = 0; f < 2; ++f) {
      const int cbi = nb * 2 + f;
      short4 ct;
      ct.x = f2bf(acc[f][0]); ct.y = f2bf(acc[f][1]);
      ct.z = f2bf(acc[f][2]); ct.w = f2bf(acc[f][3]);
      size_t a4 =
          (size_t)cbi * (NN * 16) +
          (size_t)(((m0 >> 3) + (kg >> 1)) * 128 + row * 8 + (kg & 1) * 4);
      *(short4*)((short*)hTsw1 + a4) = ct;
    }
  } else if (b < 1536) {
    // ---------------- conv -> aggT + stats ----------------
    typedef float trow[68];
    trow* tile = (trow*)smem;  // [64][68]
    const int b2 = b - 512;
    const int t0 = (b2 & 31) * 64;
    const int s0 = (b2 >> 5) * 64;
    const int sl = tid >> 4;
    const int t4 = (tid & 15) * 4;
    float w[12];
#pragma unroll
    for (int c = 0; c < 12; ++c) w[c] = conv_w[c];
    const float cb = conv_b[0];
    f32x4 acc[4];
#pragma unroll
    for (int k = 0; k < 4; ++k) acc[k] = (f32x4){cb, cb, cb, cb};
    for (int c = 0; c < 12; ++c) {
      const float* base =
          attn + (size_t)c * NN * NN + (size_t)(s0 + sl) * NN + t0 + t4;
#pragma unroll
      for (int k = 0; k < 4; ++k)
        acc[k] += w[c] * *(const f32x4*)(base + (size_t)k * 16 * NN);
    }
#pragma unroll
    for (int k = 0; k < 4; ++k) *(f32x4*)&tile[sl + 16 * k][t4] = acc[k];
    __syncthreads();
    const int tl = tid >> 2;
    const int sq = (tid & 3) * 16;
    const int tglob = t0 + tl;
    float* orow = aggT + (size_t)tglob * NN + s0 + sq;
    float psum = 0.f, pcnt = 0.f;
#pragma unroll
    for (int g = 0; g < 4; ++g) {
      f32x4 v = {tile[sq + 4 * g][tl], tile[sq + 4 * g + 1][tl],
                 tile[sq + 4 * g + 2][tl], tile[sq + 4 * g + 3][tl]};
      *(f32x4*)(orow + 4 * g) = v;
#pragma unroll
      for (int j = 0; j < 4; ++j) {
        int sglob = s0 + sq + 4 * g + j;
        bool m = (v[j] > 0.f) && (sglob != tglob);
        psum += m ? v[j] : 0.f;
        pcnt += m ? 1.f : 0.f;
      }
    }
    psum += __shfl_down(psum, 1); psum += __shfl_down(psum, 2);
    pcnt += __shfl_down(pcnt, 1); pcnt += __shfl_down(pcnt, 2);
    if ((tid & 3) == 0) {
      ssum_part[(b2 >> 5) * NN + tglob] = psum;
      scnt_part[(b2 >> 5) * NN + tglob] = pcnt;
    }
  } else if (b < 1568) {
#pragma unroll
    for (int k = 0; k < 8; ++k) {
      int o = (b - 1536) * 2048 + k * 256 + tid;
      ((short*)w2t)[o] = f2bf(W2[(o & 511) * 128 + (o >> 9)]);
    }
  } else {
    const int lane = tid & 63;
    const int wv = tid >> 6;
    float q1 = ae1[wv * 128 + lane] * We1[wv * 128 + lane] +
               ae1[wv * 128 + 64 + lane] * We1[wv * 128 + 64 + lane];
    for (int off = 32; off; off >>= 1) q1 += __shfl_down(q1, off);
    if (lane == 0) ce[wv] = q1;
    float q2 = ae2[lane] * We2[lane] + ae2[64 + lane] * We2[64 + lane];
    for (int off = 32; off; off >>= 1) q2 += __shfl_down(q2, off);
    if (tid == 0) ce[4] = q2;
  }
}

// ---------------------------------------------------------------------------
// K2 attn1: 512 blocks = 128 t-tiles x 4 heads; 4 waves = 4 s-quarters.
// mean_attr from k_pre partials. LDS reduce; write feat1b directly.
// ---------------------------------------------------------------------------
__global__ __launch_bounds__(256) void k_attn1(
    const float* __restrict__ aggT, const __hip_bfloat16* __restrict__ hTsw1,
    const float* __restrict__ sspart1, const float* __restrict__ sdpart1,
    const float* __restrict__ ssum_part, const float* __restrict__ scnt_part,
    const float* __restrict__ ce_all, const float* __restrict__ b1,
    __hip_bfloat16* __restrict__ feat1b) {
  const int tid = threadIdx.x;
  const int t0 = (int)(blockIdx.x >> 2) * 16;
  const int h = (int)(blockIdx.x & 3u);
  __shared__ float ss_sh[2048];
  __shared__ float red[4][16][128];
  __shared__ float den_sh[4][16];
  for (int i = tid; i < 2048; i += 256)
    ss_sh[i] = sspart1[(4 * h + 0) * NN + i] + sspart1[(4 * h + 1) * NN + i] +
               sspart1[(4 * h + 2) * NN + i] + sspart1[(4 * h + 3) * NN + i];
  __syncthreads();
  const int lane = tid & 63, w = tid >> 6, row = lane & 15, kg = lane >> 4;
  const int sbeg = w * 512;
  const int tRow = t0 + row;
  const float* arow = aggT + (size_t)tRow * NN;
  float msum = 0.f, mcnt = 0.f;
#pragma unroll
  for (int q = 0; q < 32; ++q) {
    msum += ssum_part[q * NN + tRow];
    mcnt += scnt_part[q * NN + tRow];
  }
  const float ma_t = msum / fmaxf(mcnt, 1.f);
  const float ce = ce_all[h];
  const float sd_t = sdpart1[(4 * h + 0) * NN + tRow] +
                     sdpart1[(4 * h + 1) * NN + tRow] +
                     sdpart1[(4 * h + 2) * NN + tRow] +
                     sdpart1[(4 * h + 3) * NN + tRow];
  const float* ssh = ss_sh + sbeg;
  const __hip_bfloat16* bbase =
      hTsw1 + (size_t)(h * 8) * (NN * 16) + kg * 128 + row * 8;
  f32x4 acc[8];
#pragma unroll
  for (int f = 0; f < 8; ++f) acc[f] = (f32x4){0.f, 0.f, 0.f, 0.f};
  float dpart = 0.f;
  for (int s0 = sbeg; s0 < sbeg + 512; s0 += 32) {
    const int sk = s0 + kg * 8;
    f32x4 a0 = *(const f32x4*)(arow + sk);
    f32x4 a1 = *(const f32x4*)(arow + sk + 4);
    f32x4 sv0 = *(const f32x4*)(ssh + (sk - sbeg));
    f32x4 sv1 = *(const f32x4*)(ssh + (sk - sbeg) + 4);
    float av[8] = {a0[0], a0[1], a0[2], a0[3], a1[0], a1[1], a1[2], a1[3]};
    float sv[8] = {sv0[0], sv0[1], sv0[2], sv0[3],
                   sv1[0], sv1[1], sv1[2], sv1[3]};
    short pb[8];
#pragma unroll
    for (int j = 0; j < 8; ++j) {
      const int s = sk + j;
      const float a = av[j];
      const bool diag = (s == tRow);
      const float ev = diag ? ma_t : a;
      const bool adj = diag || (a > 0.f);
      float l = sv[j] + sd_t + ev * ce;
      l = fmaxf(l, NEG_SLOPE * l);
      const float pv = adj ? __expf(l) : 0.f;
      dpart += pv;
      pb[j] = f2bf(pv);
    }
    bf16x8 A = {pb[0], pb[1], pb[2], pb[3], pb[4], pb[5], pb[6], pb[7]};
    const __hip_bfloat16* bp = bbase + (size_t)s0 * 16;
#pragma unroll
    for (int f = 0; f < 8; ++f) {
      bf16x8 B = *(const bf16x8*)(bp + (size_t)f * (NN * 16));
      acc[f] = __builtin_amdgcn_mfma_f32_16x16x32_bf16(A, B, acc[f], 0, 0, 0);
    }
  }
  dpart += __shfl_xor(dpart, 16);
  dpart += __shfl_xor(dpart, 32);
  __syncthreads();
#pragma unroll
  for (int f = 0; f < 8; ++f)
#pragma unroll
    for (int r = 0; r < 4; ++r) red[w][kg * 4 + r][f * 16 + row] = acc[f][r];
  if (lane < 16) den_sh[w][lane] = dpart;
  __syncthreads();
#pragma unroll
  for (int i = 0; i < 8; ++i) {
    int idx = i * 256 + tid;
    int t = idx >> 7, c = idx & 127;
    float nsum = red[0][t][c] + red[1][t][c] + red[2][t][c] + red[3][t][c];
    float dsum = den_sh[0][t] + den_sh[1][t] + den_sh[2][t] + den_sh[3][t];
    float v = nsum / dsum + b1[h * 128 + c];
    feat1b[(size_t)(t0 + t) * 512 + h * 128 + c] =
        __float2bfloat16(v > 0.f ? v : 0.f);
  }
}

// ---------------------------------------------------------------------------
// K3 gemm2: h2 = feat1b @ W2 -> hTsw2; ssrc2/sdst2 via LDS cross-wave reduce.
// ---------------------------------------------------------------------------
__global__ __launch_bounds__(256) void k_gemm2(
    const __hip_bfloat16* __restrict__ feat1b,
    const __hip_bfloat16* __restrict__ w2t, const float* __restrict__ asrc2,
    const float* __restrict__ adst2, __hip_bfloat16* __restrict__ hTsw2,
    float* __restrict__ ssrc2, float* __restrict__ sdst2) {
  const int tid = threadIdx.x;
  const int wv = tid >> 6;
  const int w = (int)blockIdx.x * 4 + wv;  // 0..511
  const int lane = tid & 63, row = lane & 15, kg = lane >> 4;
  const int mb = w >> 2, nb = w & 3;
  const int m0 = mb * 16, n0 = nb * 32;
  __shared__ float sred[2][4][16];
  const __hip_bfloat16* arow = feat1b + (size_t)(m0 + row) * 512 + kg * 8;
  f32x4 acc[2];
#pragma unroll
  for (int f = 0; f < 2; ++f) acc[f] = (f32x4){0.f, 0.f, 0.f, 0.f};
#pragma unroll
  for (int ks = 0; ks < 16; ++ks) {
    bf16x8 Af = *(const bf16x8*)(arow + ks * 32);
#pragma unroll
    for (int f = 0; f < 2; ++f) {
      bf16x8 Bf = *(const bf16x8*)(w2t + (size_t)(n0 + f * 16 + row) * 512 +
                                   kg * 8 + ks * 32);
      acc[f] = __builtin_amdgcn_mfma_f32_16x16x32_bf16(Af, Bf, acc[f], 0, 0, 0);
    }
  }
  float as[2], ad[2];
#pragma unroll
  for (int f = 0; f < 2; ++f) {
    int ch = (n0 + f * 16 + row) & 127;
    as[f] = asrc2[ch];
    ad[f] = adst2[ch];
  }
  float ps[4] = {0.f, 0.f, 0.f, 0.f}, pd[4] = {0.f, 0.f, 0.f, 0.f};
#pragma unroll
  for (int f = 0; f < 2; ++f)
#pragma unroll
    for (int r = 0; r < 4; ++r) {
      ps[r] += acc[f][r] * as[f];
      pd[r] += acc[f][r] * ad[f];
    }
#pragma unroll
  for (int m = 1; m < 16; m <<= 1) {
#pragma unroll
    for (int r = 0; r < 4; ++r) {
      ps[r] += __shfl_xor(ps[r], m);
      pd[r] += __shfl_xor(pd[r], m);
    }
  }
  if (row == 0) {
#pragma unroll
    for (int r = 0; r < 4; ++r) {
      sred[0][wv][kg * 4 + r] = ps[r];
      sred[1][wv][kg * 4 + r] = pd[r];
    }
  }
  __syncthreads();
  if (tid < 16) {
    float s = sred[0][0][tid] + sred[0][1][tid] + sred[0][2][tid] +
              sred[0][3][tid];
    float d = sred[1][0][tid] + sred[1][1][tid] + sred[1][2][tid] +
              sred[1][3][tid];
    ssrc2[(int)blockIdx.x * 16 + tid] = s;
    sdst2[(int)blockIdx.x * 16 + tid] = d;
  }
#pragma unroll
  for (int f = 0; f < 2; ++f) {
    const int cbi = nb * 2 + f;
    short4 ct;
    ct.x = f2bf(acc[f][0]); ct.y = f2bf(acc[f][1]);
    ct.z = f2bf(acc[f][2]); ct.w = f2bf(acc[f][3]);
    size_t a4 = (size_t)cbi * (NN * 16) +
                (size_t)(((m0 >> 3) + (kg >> 1)) * 128 + row * 8 + (kg & 1) * 4);
    *(short4*)((short*)hTsw2 + a4) = ct;
  }
}

// ---------------------------------------------------------------------------
// K4 attn2 (1 head): 256 blocks = 128 t-tiles x 2 col-halves; 4 waves =
// s-quarters; mean from partials; LDS reduce; write feat2 directly.
// ---------------------------------------------------------------------------
__global__ __launch_bounds__(256) void k_attn2(
    const float* __restrict__ aggT, const __hip_bfloat16* __restrict__ hTsw2,
    const float* __restrict__ ssrc2, const float* __restrict__ sdst2,
    const float* __restrict__ ssum_part, const float* __restrict__ scnt_part,
    const float* __restrict__ ce_all, const float* __restrict__ b2,
    float* __restrict__ feat2) {
  const int tid = threadIdx.x;
  const int t0 = (int)(blockIdx.x >> 1) * 16;
  const int chalf = (int)(blockIdx.x & 1u);
  __shared__ float ss_sh[2048];
  __shared__ float red[4][16][64];
  __shared__ float den_sh[4][16];
  for (int i = tid; i < 2048; i += 256) ss_sh[i] = ssrc2[i];
  __syncthreads();
  const int lane = tid & 63, w = tid >> 6, row = lane & 15, kg = lane >> 4;
  const int sbeg = w * 512;
  const int tRow = t0 + row;
  const float* arow = aggT + (size_t)tRow * NN;
  float msum = 0.f, mcnt = 0.f;
#pragma unroll
  for (int q = 0; q < 32; ++q) {
    msum += ssum_part[q * NN + tRow];
    mcnt += scnt_part[q * NN + tRow];
  }
  const float ma_t = msum / fmaxf(mcnt, 1.f);
  const float ce = ce_all[4];
  const float sd_t = sdst2[tRow];
  const float* ssh = ss_sh + sbeg;
  const __hip_bfloat16* bbase =
      hTsw2 + (size_t)(chalf * 4) * (NN * 16) + kg * 128 + row * 8;
  f32x4 acc[4];
#pragma unroll
  for (int f = 0; f < 4; ++f) acc[f] = (f32x4){0.f, 0.f, 0.f, 0.f};
  float dpart = 0.f;
  for (int s0 = sbeg; s0 < sbeg + 512; s0 += 32) {
    const int sk = s0 + kg * 8;
    f32x4 a0 = *(const f32x4*)(arow + sk);
    f32x4 a1 = *(const f32x4*)(arow + sk + 4);
    f32x4 sv0 = *(const f32x4*)(ssh + (sk - sbeg));
    f32x4 sv1 = *(const f32x4*)(ssh + (sk - sbeg) + 4);
    float av[8] = {a0[0], a0[1], a0[2], a0[3], a1[0], a1[1], a1[2], a1[3]};
    float sv[8] = {sv0[0], sv0[1], sv0[2], sv0[3],
                   sv1[0], sv1[1], sv1[2], sv1[3]};
    short pb[8];
#pragma unroll
    for (int j = 0; j < 8; ++j) {
      const int s = sk + j;
      const float a = av[j];
      const bool diag = (s == tRow);
      const float ev = diag ? ma_t : a;
      const bool adj = diag || (a > 0.f);
      float l = sv[j] + sd_t + ev * ce;
      l = fmaxf(l, NEG_SLOPE * l);
      const float pv = adj ? __expf(l) : 0.f;
      dpart += pv;
      pb[j] = f2bf(pv);
    }
    bf16x8 A = {pb[0], pb[1], pb[2], pb[3], pb[4], pb[5], pb[6], pb[7]};
    const __hip_bfloat16* bp = bbase + (size_t)s0 * 16;
#pragma unroll
    for (int f = 0; f < 4; ++f) {
      bf16x8 B = *(const bf16x8*)(bp + (size_t)f * (NN * 16));
      acc[f] = __builtin_amdgcn_mfma_f32_16x16x32_bf16(A, B, acc[f], 0, 0, 0);
    }
  }
  dpart += __shfl_xor(dpart, 16);
  dpart += __shfl_xor(dpart, 32);
  __syncthreads();
#pragma unroll
  for (int f = 0; f < 4; ++f)
#pragma unroll
    for (int r = 0; r < 4; ++r) red[w][kg * 4 + r][f * 16 + row] = acc[f][r];
  if (lane < 16) den_sh[w][lane] = dpart;
  __syncthreads();
#pragma unroll
  for (int i = 0; i < 4; ++i) {
    int idx = i * 256 + tid;
    int t = idx >> 6, c = idx & 63;
    float nsum = red[0][t][c] + red[1][t][c] + red[2][t][c] + red[3][t][c];
    float dsum = den_sh[0][t] + den_sh[1][t] + den_sh[2][t] + den_sh[3][t];
    feat2[(size_t)(t0 + t) * 128 + chalf * 64 + c] =
        nsum / dsum + b2[chalf * 64 + c];
  }
}

// ---------------------------------------------------------------------------
// K5: segment mean pool + fc + log_softmax. 8 blocks x 256 threads.
// ---------------------------------------------------------------------------
__global__ __launch_bounds__(256) void k_poolhead(
    const float* __restrict__ feat, const int* __restrict__ bidx,
    const float* __restrict__ fcw, const float* __restrict__ fcb,
    float* __restrict__ out) {
  const int g = blockIdx.x;
  const int tid = threadIdx.x;
  __shared__ int lo[2];
  __shared__ float ps2[256];
  __shared__ float lsh[10];
  if (tid == 0) { lo[0] = NN; lo[1] = NN; }
  __syncthreads();
  for (int n = tid; n < NN; n += 256) {
    int b = bidx[n];
    int bprev = (n == 0) ? -1 : bidx[n - 1];
    if (b >= g && bprev < g) atomicMin(&lo[0], n);
    if (b >= g + 1 && bprev < g + 1) atomicMin(&lo[1], n);
  }
  __syncthreads();
  int s = lo[0], e = lo[1];
  const int c = tid & 127, half = tid >> 7;
  float sum = 0.f;
  for (int n = s + half; n < e; n += 2) sum += feat[(size_t)n * 128 + c];
  ps2[tid] = sum;
  __syncthreads();
  if (tid < 128) {
    float cntf = (float)((e - s) > 1 ? (e - s) : 1);
    ps2[tid] = (ps2[tid] + ps2[tid + 128]) / cntf;
  }
  __syncthreads();
  if (tid < 10) {
    float v = fcb[tid];
    for (int ch = 0; ch < 128; ++ch) v += ps2[ch] * fcw[ch * 10 + tid];
    lsh[tid] = v;
  }
  __syncthreads();
  if (tid < 10) {
    float m = -1e30f;
    for (int i = 0; i < 10; ++i) m = fmaxf(m, lsh[i]);
    float den = 0.f;
    for (int i = 0; i < 10; ++i) den += expf(lsh[i] - m);
    out[g * 10 + tid] = lsh[tid] - m - logf(den);
  }
}

extern "C" void kernel_launch(void* const* d_in, const int* in_sizes, int n_in,
                              void* d_out, int out_size, void* d_ws,
                              size_t ws_size, hipStream_t stream) {
  (void)in_sizes; (void)n_in; (void)out_size; (void)ws_size;
  const float* x      = (const float*)d_in[0];
  const float* attn   = (const float*)d_in[1];
  const int*   bidx   = (const int*)d_in[2];
  const float* conv_w = (const float*)d_in[3];
  const float* conv_b = (const float*)d_in[4];
  const float* W1     = (const float*)d_in[5];
  const float* asrc1  = (const float*)d_in[6];
  const float* adst1  = (const float*)d_in[7];
  const float* aedge1 = (const float*)d_in[8];
  const float* We1    = (const float*)d_in[9];
  const float* b1     = (const float*)d_in[10];
  const float* W2     = (const float*)d_in[11];
  const float* asrc2  = (const float*)d_in[12];
  const float* adst2  = (const float*)d_in[13];
  const float* aedge2 = (const float*)d_in[14];
  const float* We2    = (const float*)d_in[15];
  const float* b2     = (const float*)d_in[16];
  const float* fcw    = (const float*)d_in[17];
  const float* fcb    = (const float*)d_in[18];

  float* ws = (float*)d_ws;
  float* aggT      = ws;                   // 4,194,304
  float* feat2     = aggT + 4194304;       //   262,144
  float* ssum_part = feat2 + 262144;       //    65,536 (32 x 2048)
  float* scnt_part = ssum_part + 65536;    //    65,536
  float* sspart1   = scnt_part + 65536;    //    32,768 (16 x 2048)
  float* sdpart1   = sspart1 + 32768;      //    32,768
  float* ssrc2     = sdpart1 + 32768;      //     2,048
  float* sdst2     = ssrc2 + 2048;         //     2,048
  float* ce        = sdst2 + 2048;         //        64
  float* bf        = ce + 64;
  __hip_bfloat16* w2t    = (__hip_bfloat16*)bf;             //    65,536 el
  __hip_bfloat16* hTsw1  = (__hip_bfloat16*)(bf + 32768);   // 1,048,576 el
  __hip_bfloat16* hTsw2  = (__hip_bfloat16*)(bf + 557056);  //   262,144 el
  __hip_bfloat16* feat1b = (__hip_bfloat16*)(bf + 688128);  // 1,048,576 el

  k_pre<<<1569, 256, 0, stream>>>(attn, conv_w, conv_b, x, W1, W2, asrc1,
                                  adst1, aedge1, We1, aedge2, We2, aggT,
                                  ssum_part, scnt_part, hTsw1, sspart1,
                                  sdpart1, w2t, ce);
  k_attn1<<<512, 256, 0, stream>>>(aggT, hTsw1, sspart1, sdpart1, ssum_part,
                                   scnt_part, ce, b1, feat1b);
  k_gemm2<<<128, 256, 0, stream>>>(feat1b, w2t, asrc2, adst2, hTsw2, ssrc2,
                                   sdst2);
  k_attn2<<<256, 256, 0, stream>>>(aggT, hTsw2, ssrc2, sdst2, ssum_part,
                                   scnt_part, ce, b2, feat2);
  k_poolhead<<<8, 256, 0, stream>>>(feat2, bidx, fcw, fcb, (float*)d_out);
}

// Round 13
// 124.786 us; speedup vs baseline: 7.5346x; 1.0560x over previous
//
#include <hip/hip_runtime.h>
#include <hip/hip_bf16.h>
#include <math.h>

#define NN 2048
#define NEG_SLOPE 0.2f

typedef __attribute__((ext_vector_type(8))) short bf16x8;
typedef __attribute__((ext_vector_type(4))) float f32x4;

static __device__ inline short f2bf(float x) {
  union { float f; unsigned u; } v;
  v.f = x;
  unsigned r = v.u + 0x7fffu + ((v.u >> 16) & 1u);  // RNE
  return (short)(r >> 16);
}

static __device__ inline float bf2f(short b) {
  union { unsigned u; float f; } v;
  v.u = ((unsigned)(unsigned short)b) << 16;
  return v.f;
}

// ---------------------------------------------------------------------------
// K1 k_pre: blocks 0-511: gemm1 (x @ W1, W1 staged per-block via LDS bf16-bit
// transpose) -> swizzled hTsw1 + ssrc/sdst partials. Blocks 512-1535: conv ->
// aggTb (bf16, 64x64 tile, LDS transpose) + fp32 stat partials.
// 1536-1567: w2t. 1568: ce.
// ---------------------------------------------------------------------------
__global__ __launch_bounds__(256) void k_pre(
    const float* __restrict__ attn, const float* __restrict__ conv_w,
    const float* __restrict__ conv_b, const float* __restrict__ x,
    const float* __restrict__ W1, const float* __restrict__ W2,
    const float* __restrict__ asrc1, const float* __restrict__ adst1,
    const float* __restrict__ ae1, const float* __restrict__ We1,
    const float* __restrict__ ae2, const float* __restrict__ We2,
    __hip_bfloat16* __restrict__ aggTb, float* __restrict__ ssum_part,
    float* __restrict__ scnt_part, __hip_bfloat16* __restrict__ hTsw1,
    float* __restrict__ sspart1, float* __restrict__ sdpart1,
    __hip_bfloat16* __restrict__ w2t, float* __restrict__ ce) {
  const int b = blockIdx.x;
  const int tid = threadIdx.x;
  __shared__ __align__(16) char smem[34816];
  if (b < 512) {
    // ---------------- gemm1 ----------------
    typedef short w1row[136];       // bf16 bit patterns, 272B rows (16B-align)
    w1row* w1s = (w1row*)smem;
    const int mb = b >> 2, cblk = b & 3;
    const int m0 = mb * 16;
    for (int e = tid; e < 128 * 32; e += 256) {
      int k = e >> 5, cq = (e & 31) * 4;
      f32x4 v = *(const f32x4*)(W1 + (size_t)k * 512 + cblk * 128 + cq);
#pragma unroll
      for (int j = 0; j < 4; ++j) w1s[cq + j][k] = f2bf(v[j]);
    }
    __syncthreads();
    const int wv = tid >> 6;
    const int lane = tid & 63, row = lane & 15, kg = lane >> 4;
    const int nb = cblk * 4 + wv;
    const int n0l = wv * 32;
    const float* axrow = x + (size_t)(m0 + row) * 128 + kg * 8;
    f32x4 acc[2];
#pragma unroll
    for (int f = 0; f < 2; ++f) acc[f] = (f32x4){0.f, 0.f, 0.f, 0.f};
#pragma unroll
    for (int ks = 0; ks < 4; ++ks) {
      f32x4 xa = *(const f32x4*)(axrow + ks * 32);
      f32x4 xb = *(const f32x4*)(axrow + ks * 32 + 4);
      bf16x8 Af = {f2bf(xa[0]), f2bf(xa[1]), f2bf(xa[2]), f2bf(xa[3]),
                   f2bf(xb[0]), f2bf(xb[1]), f2bf(xb[2]), f2bf(xb[3])};
#pragma unroll
      for (int f = 0; f < 2; ++f) {
        bf16x8 Bf = *(const bf16x8*)&w1s[n0l + f * 16 + row][kg * 8 + ks * 32];
        acc[f] =
            __builtin_amdgcn_mfma_f32_16x16x32_bf16(Af, Bf, acc[f], 0, 0, 0);
      }
    }
    const int h = nb >> 2;
    float as[2], ad[2];
#pragma unroll
    for (int f = 0; f < 2; ++f) {
      int ch = (n0l + f * 16 + row) & 127;
      as[f] = asrc1[h * 128 + ch];
      ad[f] = adst1[h * 128 + ch];
    }
    float ps[4] = {0.f, 0.f, 0.f, 0.f}, pd[4] = {0.f, 0.f, 0.f, 0.f};
#pragma unroll
    for (int f = 0; f < 2; ++f)
#pragma unroll
      for (int r = 0; r < 4; ++r) {
        ps[r] += acc[f][r] * as[f];
        pd[r] += acc[f][r] * ad[f];
      }
#pragma unroll
    for (int m = 1; m < 16; m <<= 1) {
#pragma unroll
      for (int r = 0; r < 4; ++r) {
        ps[r] += __shfl_xor(ps[r], m);
        pd[r] += __shfl_xor(pd[r], m);
      }
    }
    if (row == 0) {
#pragma unroll
      for (int r = 0; r < 4; ++r) {
        int node = m0 + kg * 4 + r;
        sspart1[nb * NN + node] = ps[r];
        sdpart1[nb * NN + node] = pd[r];
      }
    }
#pragma unroll
    for (int f = 0; f < 2; ++f) {
      const int cbi = nb * 2 + f;
      short4 ct;
      ct.x = f2bf(acc[f][0]); ct.y = f2bf(acc[f][1]);
      ct.z = f2bf(acc[f][2]); ct.w = f2bf(acc[f][3]);
      size_t a4 =
          (size_t)cbi * (NN * 16) +
          (size_t)(((m0 >> 3) + (kg >> 1)) * 128 + row * 8 + (kg & 1) * 4);
      *(short4*)((short*)hTsw1 + a4) = ct;
    }
  } else if (b < 1536) {
    // ---------------- conv -> aggTb (bf16) + fp32 stats ----------------
    typedef float trow[68];
    trow* tile = (trow*)smem;  // [64][68]
    const int b2 = b - 512;
    const int t0 = (b2 & 31) * 64;
    const int s0 = (b2 >> 5) * 64;
    const int sl = tid >> 4;
    const int t4 = (tid & 15) * 4;
    float w[12];
#pragma unroll
    for (int c = 0; c < 12; ++c) w[c] = conv_w[c];
    const float cb = conv_b[0];
    f32x4 acc[4];
#pragma unroll
    for (int k = 0; k < 4; ++k) acc[k] = (f32x4){cb, cb, cb, cb};
    for (int c = 0; c < 12; ++c) {
      const float* base =
          attn + (size_t)c * NN * NN + (size_t)(s0 + sl) * NN + t0 + t4;
#pragma unroll
      for (int k = 0; k < 4; ++k)
        acc[k] += w[c] * *(const f32x4*)(base + (size_t)k * 16 * NN);
    }
#pragma unroll
    for (int k = 0; k < 4; ++k) *(f32x4*)&tile[sl + 16 * k][t4] = acc[k];
    __syncthreads();
    const int tl = tid >> 2;
    const int sq = (tid & 3) * 16;
    const int tglob = t0 + tl;
    float psum = 0.f, pcnt = 0.f;
    short bb[16];
#pragma unroll
    for (int g = 0; g < 4; ++g) {
      f32x4 v = {tile[sq + 4 * g][tl], tile[sq + 4 * g + 1][tl],
                 tile[sq + 4 * g + 2][tl], tile[sq + 4 * g + 3][tl]};
#pragma unroll
      for (int j = 0; j < 4; ++j) {
        bb[4 * g + j] = f2bf(v[j]);
        int sglob = s0 + sq + 4 * g + j;
        bool m = (v[j] > 0.f) && (sglob != tglob);
        psum += m ? v[j] : 0.f;
        pcnt += m ? 1.f : 0.f;
      }
    }
    {
      short* orow = (short*)aggTb + (size_t)tglob * NN + s0 + sq;
      bf16x8 lo = {bb[0], bb[1], bb[2], bb[3], bb[4], bb[5], bb[6], bb[7]};
      bf16x8 hi = {bb[8], bb[9], bb[10], bb[11], bb[12], bb[13], bb[14], bb[15]};
      *(bf16x8*)orow = lo;
      *(bf16x8*)(orow + 8) = hi;
    }
    psum += __shfl_down(psum, 1); psum += __shfl_down(psum, 2);
    pcnt += __shfl_down(pcnt, 1); pcnt += __shfl_down(pcnt, 2);
    if ((tid & 3) == 0) {
      ssum_part[(b2 >> 5) * NN + tglob] = psum;
      scnt_part[(b2 >> 5) * NN + tglob] = pcnt;
    }
  } else if (b < 1568) {
#pragma unroll
    for (int k = 0; k < 8; ++k) {
      int o = (b - 1536) * 2048 + k * 256 + tid;
      ((short*)w2t)[o] = f2bf(W2[(o & 511) * 128 + (o >> 9)]);
    }
  } else {
    const int lane = tid & 63;
    const int wv = tid >> 6;
    float q1 = ae1[wv * 128 + lane] * We1[wv * 128 + lane] +
               ae1[wv * 128 + 64 + lane] * We1[wv * 128 + 64 + lane];
    for (int off = 32; off; off >>= 1) q1 += __shfl_down(q1, off);
    if (lane == 0) ce[wv] = q1;
    float q2 = ae2[lane] * We2[lane] + ae2[64 + lane] * We2[64 + lane];
    for (int off = 32; off; off >>= 1) q2 += __shfl_down(q2, off);
    if (tid == 0) ce[4] = q2;
  }
}

// ---------------------------------------------------------------------------
// K2 attn1: 512 blocks = 128 t-tiles x 4 heads; 4 waves = 4 s-quarters.
// bf16 aggTb loads (1x 16B / 8 s); f2bf A-frag; cooperative mean_attr.
// ---------------------------------------------------------------------------
__global__ __launch_bounds__(256) void k_attn1(
    const __hip_bfloat16* __restrict__ aggTb,
    const __hip_bfloat16* __restrict__ hTsw1,
    const float* __restrict__ sspart1, const float* __restrict__ sdpart1,
    const float* __restrict__ ssum_part, const float* __restrict__ scnt_part,
    const float* __restrict__ ce_all, const float* __restrict__ b1,
    __hip_bfloat16* __restrict__ feat1b) {
  const int tid = threadIdx.x;
  const int t0 = (int)(blockIdx.x >> 2) * 16;
  const int h = (int)(blockIdx.x & 3u);
  __shared__ float ss_sh[2048];
  __shared__ float red[4][16][128];
  __shared__ float den_sh[4][16];
  __shared__ float mp_sh[2][16][16];
  __shared__ float ma_sh[16];
  for (int i = tid; i < 2048; i += 256)
    ss_sh[i] = sspart1[(4 * h + 0) * NN + i] + sspart1[(4 * h + 1) * NN + i] +
               sspart1[(4 * h + 2) * NN + i] + sspart1[(4 * h + 3) * NN + i];
  {
    int r = tid & 15, q2 = tid >> 4;  // q2: 0..15
    float s_ = ssum_part[(size_t)(2 * q2) * NN + t0 + r] +
               ssum_part[(size_t)(2 * q2 + 1) * NN + t0 + r];
    float c_ = scnt_part[(size_t)(2 * q2) * NN + t0 + r] +
               scnt_part[(size_t)(2 * q2 + 1) * NN + t0 + r];
    mp_sh[0][q2][r] = s_;
    mp_sh[1][q2][r] = c_;
  }
  __syncthreads();
  if (tid < 16) {
    float s_ = 0.f, c_ = 0.f;
#pragma unroll
    for (int q = 0; q < 16; ++q) { s_ += mp_sh[0][q][tid]; c_ += mp_sh[1][q][tid]; }
    ma_sh[tid] = s_ / fmaxf(c_, 1.f);
  }
  __syncthreads();
  const int lane = tid & 63, w = tid >> 6, row = lane & 15, kg = lane >> 4;
  const int sbeg = w * 512;
  const int tRow = t0 + row;
  const float ma_t = ma_sh[row];
  const float ce = ce_all[h];
  const float sd_t = sdpart1[(4 * h + 0) * NN + tRow] +
                     sdpart1[(4 * h + 1) * NN + tRow] +
                     sdpart1[(4 * h + 2) * NN + tRow] +
                     sdpart1[(4 * h + 3) * NN + tRow];
  const short* arowb = (const short*)aggTb + (size_t)tRow * NN;
  const float* ssh = ss_sh + sbeg;
  const __hip_bfloat16* bbase =
      hTsw1 + (size_t)(h * 8) * (NN * 16) + kg * 128 + row * 8;
  f32x4 acc[8];
#pragma unroll
  for (int f = 0; f < 8; ++f) acc[f] = (f32x4){0.f, 0.f, 0.f, 0.f};
  float dpart = 0.f;
  for (int s0 = sbeg; s0 < sbeg + 512; s0 += 32) {
    const int sk = s0 + kg * 8;
    bf16x8 araw = *(const bf16x8*)(arowb + sk);
    f32x4 sv0 = *(const f32x4*)(ssh + (sk - sbeg));
    f32x4 sv1 = *(const f32x4*)(ssh + (sk - sbeg) + 4);
    float sv[8] = {sv0[0], sv0[1], sv0[2], sv0[3],
                   sv1[0], sv1[1], sv1[2], sv1[3]};
    short pb[8];
#pragma unroll
    for (int j = 0; j < 8; ++j) {
      const int s = sk + j;
      const float a = bf2f(araw[j]);
      const bool diag = (s == tRow);
      const float ev = diag ? ma_t : a;
      const bool adj = diag || (a > 0.f);
      float l = sv[j] + sd_t + ev * ce;
      l = fmaxf(l, NEG_SLOPE * l);
      const float p = adj ? __expf(l) : 0.f;
      dpart += p;
      pb[j] = f2bf(p);
    }
    bf16x8 A = {pb[0], pb[1], pb[2], pb[3], pb[4], pb[5], pb[6], pb[7]};
    const __hip_bfloat16* bp = bbase + (size_t)s0 * 16;
#pragma unroll
    for (int f = 0; f < 8; ++f) {
      bf16x8 B = *(const bf16x8*)(bp + (size_t)f * (NN * 16));
      acc[f] = __builtin_amdgcn_mfma_f32_16x16x32_bf16(A, B, acc[f], 0, 0, 0);
    }
  }
  dpart += __shfl_xor(dpart, 16);
  dpart += __shfl_xor(dpart, 32);
  __syncthreads();
#pragma unroll
  for (int f = 0; f < 8; ++f)
#pragma unroll
    for (int r = 0; r < 4; ++r) red[w][kg * 4 + r][f * 16 + row] = acc[f][r];
  if (lane < 16) den_sh[w][lane] = dpart;
  __syncthreads();
#pragma unroll
  for (int i = 0; i < 8; ++i) {
    int idx = i * 256 + tid;
    int t = idx >> 7, c = idx & 127;
    float nsum = red[0][t][c] + red[1][t][c] + red[2][t][c] + red[3][t][c];
    float dsum = den_sh[0][t] + den_sh[1][t] + den_sh[2][t] + den_sh[3][t];
    float v = nsum / dsum + b1[h * 128 + c];
    feat1b[(size_t)(t0 + t) * 512 + h * 128 + c] =
        __float2bfloat16(v > 0.f ? v : 0.f);
  }
}

// ---------------------------------------------------------------------------
// K3 gemm2: h2 = feat1b @ W2 -> hTsw2; ssrc2/sdst2 via LDS cross-wave reduce.
// ---------------------------------------------------------------------------
__global__ __launch_bounds__(256) void k_gemm2(
    const __hip_bfloat16* __restrict__ feat1b,
    const __hip_bfloat16* __restrict__ w2t, const float* __restrict__ asrc2,
    const float* __restrict__ adst2, __hip_bfloat16* __restrict__ hTsw2,
    float* __restrict__ ssrc2, float* __restrict__ sdst2) {
  const int tid = threadIdx.x;
  const int wv = tid >> 6;
  const int w = (int)blockIdx.x * 4 + wv;  // 0..511
  const int lane = tid & 63, row = lane & 15, kg = lane >> 4;
  const int mb = w >> 2, nb = w & 3;
  const int m0 = mb * 16, n0 = nb * 32;
  __shared__ float sred[2][4][16];
  const __hip_bfloat16* arow = feat1b + (size_t)(m0 + row) * 512 + kg * 8;
  f32x4 acc[2];
#pragma unroll
  for (int f = 0; f < 2; ++f) acc[f] = (f32x4){0.f, 0.f, 0.f, 0.f};
#pragma unroll
  for (int ks = 0; ks < 16; ++ks) {
    bf16x8 Af = *(const bf16x8*)(arow + ks * 32);
#pragma unroll
    for (int f = 0; f < 2; ++f) {
      bf16x8 Bf = *(const bf16x8*)(w2t + (size_t)(n0 + f * 16 + row) * 512 +
                                   kg * 8 + ks * 32);
      acc[f] = __builtin_amdgcn_mfma_f32_16x16x32_bf16(Af, Bf, acc[f], 0, 0, 0);
    }
  }
  float as[2], ad[2];
#pragma unroll
  for (int f = 0; f < 2; ++f) {
    int ch = (n0 + f * 16 + row) & 127;
    as[f] = asrc2[ch];
    ad[f] = adst2[ch];
  }
  float ps[4] = {0.f, 0.f, 0.f, 0.f}, pd[4] = {0.f, 0.f, 0.f, 0.f};
#pragma unroll
  for (int f = 0; f < 2; ++f)
#pragma unroll
    for (int r = 0; r < 4; ++r) {
      ps[r] += acc[f][r] * as[f];
      pd[r] += acc[f][r] * ad[f];
    }
#pragma unroll
  for (int m = 1; m < 16; m <<= 1) {
#pragma unroll
    for (int r = 0; r < 4; ++r) {
      ps[r] += __shfl_xor(ps[r], m);
      pd[r] += __shfl_xor(pd[r], m);
    }
  }
  if (row == 0) {
#pragma unroll
    for (int r = 0; r < 4; ++r) {
      sred[0][wv][kg * 4 + r] = ps[r];
      sred[1][wv][kg * 4 + r] = pd[r];
    }
  }
  __syncthreads();
  if (tid < 16) {
    float s = sred[0][0][tid] + sred[0][1][tid] + sred[0][2][tid] +
              sred[0][3][tid];
    float d = sred[1][0][tid] + sred[1][1][tid] + sred[1][2][tid] +
              sred[1][3][tid];
    ssrc2[(int)blockIdx.x * 16 + tid] = s;
    sdst2[(int)blockIdx.x * 16 + tid] = d;
  }
#pragma unroll
  for (int f = 0; f < 2; ++f) {
    const int cbi = nb * 2 + f;
    short4 ct;
    ct.x = f2bf(acc[f][0]); ct.y = f2bf(acc[f][1]);
    ct.z = f2bf(acc[f][2]); ct.w = f2bf(acc[f][3]);
    size_t a4 = (size_t)cbi * (NN * 16) +
                (size_t)(((m0 >> 3) + (kg >> 1)) * 128 + row * 8 + (kg & 1) * 4);
    *(short4*)((short*)hTsw2 + a4) = ct;
  }
}

// ---------------------------------------------------------------------------
// K4 attn2 (1 head): 256 blocks = 128 t-tiles x 2 col-halves; 4 waves =
// s-quarters; bf16 aggTb; f2bf A-frag; cooperative mean; write feat2 direct.
// ---------------------------------------------------------------------------
__global__ __launch_bounds__(256) void k_attn2(
    const __hip_bfloat16* __restrict__ aggTb,
    const __hip_bfloat16* __restrict__ hTsw2,
    const float* __restrict__ ssrc2, const float* __restrict__ sdst2,
    const float* __restrict__ ssum_part, const float* __restrict__ scnt_part,
    const float* __restrict__ ce_all, const float* __restrict__ b2,
    float* __restrict__ feat2) {
  const int tid = threadIdx.x;
  const int t0 = (int)(blockIdx.x >> 1) * 16;
  const int chalf = (int)(blockIdx.x & 1u);
  __shared__ float ss_sh[2048];
  __shared__ float red[4][16][64];
  __shared__ float den_sh[4][16];
  __shared__ float mp_sh[2][16][16];
  __shared__ float ma_sh[16];
  for (int i = tid; i < 2048; i += 256) ss_sh[i] = ssrc2[i];
  {
    int r = tid & 15, q2 = tid >> 4;
    float s_ = ssum_part[(size_t)(2 * q2) * NN + t0 + r] +
               ssum_part[(size_t)(2 * q2 + 1) * NN + t0 + r];
    float c_ = scnt_part[(size_t)(2 * q2) * NN + t0 + r] +
               scnt_part[(size_t)(2 * q2 + 1) * NN + t0 + r];
    mp_sh[0][q2][r] = s_;
    mp_sh[1][q2][r] = c_;
  }
  __syncthreads();
  if (tid < 16) {
    float s_ = 0.f, c_ = 0.f;
#pragma unroll
    for (int q = 0; q < 16; ++q) { s_ += mp_sh[0][q][tid]; c_ += mp_sh[1][q][tid]; }
    ma_sh[tid] = s_ / fmaxf(c_, 1.f);
  }
  __syncthreads();
  const int lane = tid & 63, w = tid >> 6, row = lane & 15, kg = lane >> 4;
  const int sbeg = w * 512;
  const int tRow = t0 + row;
  const float ma_t = ma_sh[row];
  const float ce = ce_all[4];
  const float sd_t = sdst2[tRow];
  const short* arowb = (const short*)aggTb + (size_t)tRow * NN;
  const float* ssh = ss_sh + sbeg;
  const __hip_bfloat16* bbase =
      hTsw2 + (size_t)(chalf * 4) * (NN * 16) + kg * 128 + row * 8;
  f32x4 acc[4];
#pragma unroll
  for (int f = 0; f < 4; ++f) acc[f] = (f32x4){0.f, 0.f, 0.f, 0.f};
  float dpart = 0.f;
  for (int s0 = sbeg; s0 < sbeg + 512; s0 += 32) {
    const int sk = s0 + kg * 8;
    bf16x8 araw = *(const bf16x8*)(arowb + sk);
    f32x4 sv0 = *(const f32x4*)(ssh + (sk - sbeg));
    f32x4 sv1 = *(const f32x4*)(ssh + (sk - sbeg) + 4);
    float sv[8] = {sv0[0], sv0[1], sv0[2], sv0[3],
                   sv1[0], sv1[1], sv1[2], sv1[3]};
    short pb[8];
#pragma unroll
    for (int j = 0; j < 8; ++j) {
      const int s = sk + j;
      const float a = bf2f(araw[j]);
      const bool diag = (s == tRow);
      const float ev = diag ? ma_t : a;
      const bool adj = diag || (a > 0.f);
      float l = sv[j] + sd_t + ev * ce;
      l = fmaxf(l, NEG_SLOPE * l);
      const float p = adj ? __expf(l) : 0.f;
      dpart += p;
      pb[j] = f2bf(p);
    }
    bf16x8 A = {pb[0], pb[1], pb[2], pb[3], pb[4], pb[5], pb[6], pb[7]};
    const __hip_bfloat16* bp = bbase + (size_t)s0 * 16;
#pragma unroll
    for (int f = 0; f < 4; ++f) {
      bf16x8 B = *(const bf16x8*)(bp + (size_t)f * (NN * 16));
      acc[f] = __builtin_amdgcn_mfma_f32_16x16x32_bf16(A, B, acc[f], 0, 0, 0);
    }
  }
  dpart += __shfl_xor(dpart, 16);
  dpart += __shfl_xor(dpart, 32);
  __syncthreads();
#pragma unroll
  for (int f = 0; f < 4; ++f)
#pragma unroll
    for (int r = 0; r < 4; ++r) red[w][kg * 4 + r][f * 16 + row] = acc[f][r];
  if (lane < 16) den_sh[w][lane] = dpart;
  __syncthreads();
#pragma unroll
  for (int i = 0; i < 4; ++i) {
    int idx = i * 256 + tid;
    int t = idx >> 6, c = idx & 63;
    float nsum = red[0][t][c] + red[1][t][c] + red[2][t][c] + red[3][t][c];
    float dsum = den_sh[0][t] + den_sh[1][t] + den_sh[2][t] + den_sh[3][t];
    feat2[(size_t)(t0 + t) * 128 + chalf * 64 + c] =
        nsum / dsum + b2[chalf * 64 + c];
  }
}

// ---------------------------------------------------------------------------
// K5: segment mean pool + fc + log_softmax. 8 blocks x 256 threads.
// ---------------------------------------------------------------------------
__global__ __launch_bounds__(256) void k_poolhead(
    const float* __restrict__ feat, const int* __restrict__ bidx,
    const float* __restrict__ fcw, const float* __restrict__ fcb,
    float* __restrict__ out) {
  const int g = blockIdx.x;
  const int tid = threadIdx.x;
  __shared__ int lo[2];
  __shared__ float ps2[256];
  __shared__ float lsh[10];
  if (tid == 0) { lo[0] = NN; lo[1] = NN; }
  __syncthreads();
  for (int n = tid; n < NN; n += 256) {
    int b = bidx[n];
    int bprev = (n == 0) ? -1 : bidx[n - 1];
    if (b >= g && bprev < g) atomicMin(&lo[0], n);
    if (b >= g + 1 && bprev < g + 1) atomicMin(&lo[1], n);
  }
  __syncthreads();
  int s = lo[0], e = lo[1];
  const int c = tid & 127, half = tid >> 7;
  float sum = 0.f;
  for (int n = s + half; n < e; n += 2) sum += feat[(size_t)n * 128 + c];
  ps2[tid] = sum;
  __syncthreads();
  if (tid < 128) {
    float cntf = (float)((e - s) > 1 ? (e - s) : 1);
    ps2[tid] = (ps2[tid] + ps2[tid + 128]) / cntf;
  }
  __syncthreads();
  if (tid < 10) {
    float v = fcb[tid];
    for (int ch = 0; ch < 128; ++ch) v += ps2[ch] * fcw[ch * 10 + tid];
    lsh[tid] = v;
  }
  __syncthreads();
  if (tid < 10) {
    float m = -1e30f;
    for (int i = 0; i < 10; ++i) m = fmaxf(m, lsh[i]);
    float den = 0.f;
    for (int i = 0; i < 10; ++i) den += expf(lsh[i] - m);
    out[g * 10 + tid] = lsh[tid] - m - logf(den);
  }
}

extern "C" void kernel_launch(void* const* d_in, const int* in_sizes, int n_in,
                              void* d_out, int out_size, void* d_ws,
                              size_t ws_size, hipStream_t stream) {
  (void)in_sizes; (void)n_in; (void)out_size; (void)ws_size;
  const float* x      = (const float*)d_in[0];
  const float* attn   = (const float*)d_in[1];
  const int*   bidx   = (const int*)d_in[2];
  const float* conv_w = (const float*)d_in[3];
  const float* conv_b = (const float*)d_in[4];
  const float* W1     = (const float*)d_in[5];
  const float* asrc1  = (const float*)d_in[6];
  const float* adst1  = (const float*)d_in[7];
  const float* aedge1 = (const float*)d_in[8];
  const float* We1    = (const float*)d_in[9];
  const float* b1     = (const float*)d_in[10];
  const float* W2     = (const float*)d_in[11];
  const float* asrc2  = (const float*)d_in[12];
  const float* adst2  = (const float*)d_in[13];
  const float* aedge2 = (const float*)d_in[14];
  const float* We2    = (const float*)d_in[15];
  const float* b2     = (const float*)d_in[16];
  const float* fcw    = (const float*)d_in[17];
  const float* fcb    = (const float*)d_in[18];

  float* ws = (float*)d_ws;
  __hip_bfloat16* aggTb = (__hip_bfloat16*)ws;  // 4,194,304 el (2,097,152 fl)
  float* feat2     = ws + 2097152;         //   262,144
  float* ssum_part = feat2 + 262144;       //    65,536 (32 x 2048)
  float* scnt_part = ssum_part + 65536;    //    65,536
  float* sspart1   = scnt_part + 65536;    //    32,768 (16 x 2048)
  float* sdpart1   = sspart1 + 32768;      //    32,768
  float* ssrc2     = sdpart1 + 32768;      //     2,048
  float* sdst2     = ssrc2 + 2048;         //     2,048
  float* ce        = sdst2 + 2048;         //        64
  float* bf        = ce + 64;
  __hip_bfloat16* w2t    = (__hip_bfloat16*)bf;             //    65,536 el
  __hip_bfloat16* hTsw1  = (__hip_bfloat16*)(bf + 32768);   // 1,048,576 el
  __hip_bfloat16* hTsw2  = (__hip_bfloat16*)(bf + 557056);  //   262,144 el
  __hip_bfloat16* feat1b = (__hip_bfloat16*)(bf + 688128);  // 1,048,576 el

  k_pre<<<1569, 256, 0, stream>>>(attn, conv_w, conv_b, x, W1, W2, asrc1,
                                  adst1, aedge1, We1, aedge2, We2, aggTb,
                                  ssum_part, scnt_part, hTsw1, sspart1,
                                  sdpart1, w2t, ce);
  k_attn1<<<512, 256, 0, stream>>>(aggTb, hTsw1, sspart1, sdpart1, ssum_part,
                                   scnt_part, ce, b1, feat1b);
  k_gemm2<<<128, 256, 0, stream>>>(feat1b, w2t, asrc2, adst2, hTsw2, ssrc2,
                                   sdst2);
  k_attn2<<<256, 256, 0, stream>>>(aggTb, hTsw2, ssrc2, sdst2, ssum_part,
                                   scnt_part, ce, b2, feat2);
  k_poolhead<<<8, 256, 0, stream>>>(feat2, bidx, fcw, fcb, (float*)d_out);
}